// Round 4
// baseline (4072.821 us; speedup 1.0000x reference)
//
#include <hip/hip_runtime.h>
#include <cmath>

#define B_ 64
#define P_ 196
#define ENC_ 2048
#define DEC_ 1024
#define V_ 10000
#define MAXLEN_ 20
#define TDEC_ 19

typedef __attribute__((ext_vector_type(8))) short bf16x8;
typedef __attribute__((ext_vector_type(4))) float f32x4;

// ---------------- static device buffers ----------------
__device__ __align__(16) short g_encb[(size_t)12544 * 2048];   // sorted enc, bf16
__device__ __align__(16) short g_att1[(size_t)12544 * 1024];   // att1, bf16 (incl. be)
__device__ __align__(16) short g_Wcat1[(size_t)4096 * 5120];   // [Wih1(4096) | Whh1(1024)]
__device__ __align__(16) short g_Wcat2[(size_t)4096 * 4096];   // [Wih2(3072) | Whh2(1024)]
__device__ __align__(16) short g_Web[(size_t)1024 * 2048];
__device__ __align__(16) short g_Wdb[(size_t)1024 * 1024];
__device__ __align__(16) short g_Wfc1b[(size_t)10000 * 1024];
__device__ __align__(16) short g_Wfcb[(size_t)10000 * 1024];
__device__ __align__(16) short g_xc1[(size_t)20 * 64 * 5120];  // per-t [h2|em|emb_t|h1]
__device__ __align__(16) short g_xc2[64 * 4096];               // [awe | h1 | h2]
__device__ __align__(16) short g_em[64 * 2048];                // enc mean, bf16
__device__ __align__(16) float g_part[(size_t)4 * 64 * 4096];
__device__ __align__(16) float g_att2p[2 * 64 * 1024];
__device__ __align__(16) float g_c1[64 * 1024];
__device__ __align__(16) float g_c2[64 * 1024];
__device__ int g_ibuf[64 + 64 + 64 * MAXLEN_];

__device__ __forceinline__ short f2b(float f) {
  unsigned u = __float_as_uint(f);
  u += 0x7FFFu + ((u >> 16) & 1u);
  return (short)(u >> 16);
}
__device__ __forceinline__ float b2f(short s) {
  return __uint_as_float(((unsigned)(unsigned short)s) << 16);
}

// ---------------- sort + int-ish outputs ----------------
__global__ void k_sort(const int* __restrict__ cl_in, const int* __restrict__ caps_in,
                       int* __restrict__ sind, int* __restrict__ declen, int* __restrict__ caps_s,
                       float* __restrict__ out_caps, float* __restrict__ out_declen,
                       float* __restrict__ out_sind) {
  int i = threadIdx.x;  // 64 threads
  __shared__ int cl[B_];
  cl[i] = cl_in[i];
  __syncthreads();
  int my = cl[i], pos = 0;
  for (int j = 0; j < B_; ++j) {
    int cj = cl[j];
    if (cj > my || (cj == my && j < i)) pos++;
  }
  sind[pos] = i;
  __syncthreads();
  int sb = sind[i];
  int dl = cl[sb] - 1;
  declen[i] = dl;
  out_declen[i] = (float)dl;
  out_sind[i] = (float)sb;
  for (int t = 0; t < MAXLEN_; ++t) {
    int v = caps_in[sb * MAXLEN_ + t];
    caps_s[i * MAXLEN_ + t] = v;
    out_caps[i * MAXLEN_ + t] = (float)v;
  }
}

// gather-sort + fp32->bf16 convert encoder
__global__ __launch_bounds__(256) void k_encprep(const float* __restrict__ enc,
                                                 const int* __restrict__ sind,
                                                 short* __restrict__ encb) {
  int mg = blockIdx.x;  // 12544
  int b = mg / P_, p = mg - b * P_;
  const float* src = enc + ((size_t)sind[b] * P_ + p) * ENC_ + threadIdx.x * 8;
  short* dst = encb + (size_t)mg * ENC_ + threadIdx.x * 8;
  float4 a = *(const float4*)src;
  float4 c = *(const float4*)(src + 4);
  bf16x8 v;
  v[0] = f2b(a.x); v[1] = f2b(a.y); v[2] = f2b(a.z); v[3] = f2b(a.w);
  v[4] = f2b(c.x); v[5] = f2b(c.y); v[6] = f2b(c.z); v[7] = f2b(c.w);
  *(bf16x8*)dst = v;
}

// enc mean (over bf16 enc) -> g_em (bf16)
__global__ __launch_bounds__(256) void k_encmeanb(const short* __restrict__ encb,
                                                  short* __restrict__ em) {
  int b = blockIdx.x;
  int col0 = threadIdx.x * 8;
  const short* src = encb + (size_t)b * P_ * ENC_ + col0;
  float acc[8] = {};
  for (int p = 0; p < P_; ++p) {
    bf16x8 v = *(const bf16x8*)(src + (size_t)p * ENC_);
#pragma unroll
    for (int j = 0; j < 8; ++j) acc[j] += b2f(v[j]);
  }
#pragma unroll
  for (int j = 0; j < 8; ++j) em[b * 2048 + col0 + j] = f2b(acc[j] * (1.0f / 196.0f));
}

// prefill em + emb slots of every per-t xc1 buffer
__global__ __launch_bounds__(256) void k_prefill(const float* __restrict__ emb,
                                                 const int* __restrict__ caps_s,
                                                 const short* __restrict__ em,
                                                 short* __restrict__ xc1all) {
  int t = blockIdx.x, b = blockIdx.y, tid = threadIdx.x;  // (19, 64)
  short* xr = xc1all + ((size_t)t * 64 + b) * 5120;
  int i = tid * 8;
  *(bf16x8*)(xr + 1024 + i) = *(const bf16x8*)(em + b * 2048 + i);
  int cap = caps_s[b * MAXLEN_ + t];
  int j = tid * 4;
  float4 v = *(const float4*)(emb + (size_t)cap * 1024 + j);
  short4 o;
  o.x = f2b(v.x); o.y = f2b(v.y); o.z = f2b(v.z); o.w = f2b(v.w);
  *(short4*)(xr + 3072 + j) = o;
}

// strided fp32 -> bf16 weight convert: dst[r*ld+off+k] = src[r*K+k]
__global__ void k_f2bs(const float* __restrict__ src, int K, short* __restrict__ dst,
                       int ld, int off) {
  long long idx = (long long)(blockIdx.x * 256 + threadIdx.x) * 8;
  int r = (int)(idx / K), k = (int)(idx % K);
  const float* s = src + (size_t)r * K + k;
  float4 a = *(const float4*)s;
  float4 c = *(const float4*)(s + 4);
  bf16x8 v;
  v[0] = f2b(a.x); v[1] = f2b(a.y); v[2] = f2b(a.z); v[3] = f2b(a.w);
  v[4] = f2b(c.x); v[5] = f2b(c.y); v[6] = f2b(c.z); v[7] = f2b(c.w);
  *(bf16x8*)(dst + (size_t)r * ld + off + k) = v;
}

// ---------------- att1 = encb @ We^T + be -> bf16 (12544x1024, K=2048) ----------------
__global__ __launch_bounds__(512) void k_att1_mfma(const short* __restrict__ A,
                                                   const short* __restrict__ W,
                                                   const float* __restrict__ be,
                                                   short* __restrict__ Cb) {
  int wave = threadIdx.x >> 6, lane = threadIdx.x & 63;
  int m0 = blockIdx.x * 128 + (wave >> 2) * 64;
  int n0 = blockIdx.y * 256 + (wave & 3) * 64;
  int lr = lane & 15, lk = (lane >> 4) * 8;
  f32x4 acc[4][4] = {};
  const short* Ab = A + (size_t)(m0 + lr) * ENC_ + lk;
  const short* Wb = W + (size_t)(n0 + lr) * ENC_ + lk;
  for (int k0 = 0; k0 < ENC_; k0 += 32) {
    bf16x8 a[4], b[4];
#pragma unroll
    for (int i = 0; i < 4; ++i) a[i] = *(const bf16x8*)(Ab + (size_t)i * 16 * ENC_ + k0);
#pragma unroll
    for (int j = 0; j < 4; ++j) b[j] = *(const bf16x8*)(Wb + (size_t)j * 16 * ENC_ + k0);
#pragma unroll
    for (int i = 0; i < 4; ++i)
#pragma unroll
      for (int j = 0; j < 4; ++j)
        acc[i][j] = __builtin_amdgcn_mfma_f32_16x16x32_bf16(a[i], b[j], acc[i][j], 0, 0, 0);
  }
  int rr = (lane >> 4) * 4, cc = lane & 15;
#pragma unroll
  for (int i = 0; i < 4; ++i)
#pragma unroll
    for (int j = 0; j < 4; ++j) {
      int n = n0 + j * 16 + cc;
      float bn = be[n];
#pragma unroll
      for (int r = 0; r < 4; ++r) {
        int m = m0 + i * 16 + rr + r;
        Cb[(size_t)m * 1024 + n] = f2b(acc[i][j][r] + bn);
      }
    }
}

// ---------------- generic skinny MFMA GEMM: part[s][64][N] = A[64xK] @ W[NxK]^T chunk ----------------
__global__ __launch_bounds__(256) void k_skinny(const short* __restrict__ A, int lda,
                                                const short* __restrict__ W, int ldw,
                                                int N, int kchunk, float* __restrict__ part) {
  int wave = threadIdx.x >> 6, lane = threadIdx.x & 63;
  int n0 = blockIdx.x * 128 + wave * 32;
  int kb = blockIdx.y * kchunk;
  int lr = lane & 15, lk = (lane >> 4) * 8;
  f32x4 acc[4][2] = {};
  const short* Ab = A + (size_t)lr * lda + kb + lk;
  int nr0 = n0 + lr, nr1 = n0 + 16 + lr;
  bool ok0 = nr0 < N, ok1 = nr1 < N;
  const short* Wb0 = W + (size_t)(ok0 ? nr0 : 0) * ldw + kb + lk;
  const short* Wb1 = W + (size_t)(ok1 ? nr1 : 0) * ldw + kb + lk;
  const bf16x8 zv = {0, 0, 0, 0, 0, 0, 0, 0};
  for (int k0 = 0; k0 < kchunk; k0 += 32) {
    bf16x8 a[4], b0, b1;
#pragma unroll
    for (int i = 0; i < 4; ++i) a[i] = *(const bf16x8*)(Ab + (size_t)i * 16 * lda + k0);
    b0 = ok0 ? *(const bf16x8*)(Wb0 + k0) : zv;
    b1 = ok1 ? *(const bf16x8*)(Wb1 + k0) : zv;
#pragma unroll
    for (int i = 0; i < 4; ++i) {
      acc[i][0] = __builtin_amdgcn_mfma_f32_16x16x32_bf16(a[i], b0, acc[i][0], 0, 0, 0);
      acc[i][1] = __builtin_amdgcn_mfma_f32_16x16x32_bf16(a[i], b1, acc[i][1], 0, 0, 0);
    }
  }
  float* po = part + (size_t)blockIdx.y * 64 * N;
  int rr = (lane >> 4) * 4, cc = lane & 15;
#pragma unroll
  for (int i = 0; i < 4; ++i)
#pragma unroll
    for (int j = 0; j < 2; ++j) {
      int n = n0 + j * 16 + cc;
      if (n < N) {
#pragma unroll
        for (int r = 0; r < 4; ++r) {
          int m = i * 16 + rr + r;
          po[(size_t)m * N + n] = acc[i][j][r];
        }
      }
    }
}

// ---------------- LSTM gates: sum 4 partials + biases, update c, forward h (bf16) ----------------
__global__ void k_gates(const float* __restrict__ part, const float* __restrict__ bih,
                        const float* __restrict__ bhh, float* __restrict__ c,
                        const short* __restrict__ hold, int ldo,
                        short* __restrict__ dst1, int ld1,
                        short* __restrict__ dst2, int ld2,
                        const int* __restrict__ declen, int t) {
  int idx = blockIdx.x * 256 + threadIdx.x;  // 65536
  int b = idx >> 10, j = idx & 1023;
  const float* pb = part + (size_t)b * 4096;
  float gi = bih[j] + bhh[j];
  float gf = bih[1024 + j] + bhh[1024 + j];
  float gg = bih[2048 + j] + bhh[2048 + j];
  float go = bih[3072 + j] + bhh[3072 + j];
#pragma unroll
  for (int s = 0; s < 4; ++s) {
    const float* p = pb + (size_t)s * 64 * 4096;
    gi += p[j]; gf += p[j + 1024]; gg += p[j + 2048]; go += p[j + 3072];
  }
  float si = 1.0f / (1.0f + expf(-gi));
  float sf = 1.0f / (1.0f + expf(-gf));
  float so = 1.0f / (1.0f + expf(-go));
  float cn = sf * c[idx] + si * tanhf(gg);
  float hn = so * tanhf(cn);
  short hb;
  if (t < declen[b]) {
    c[idx] = cn;
    hb = f2b(hn);
  } else {
    hb = hold[b * ldo + j];
  }
  dst1[b * ld1 + j] = hb;
  dst2[b * ld2 + j] = hb;
}

// ---------------- fused attention: e -> softmax -> awe (one block per batch) ----------------
__global__ __launch_bounds__(256) void k_esa(const short* __restrict__ att1,
                                             const float* __restrict__ att2p,
                                             const float* __restrict__ bd,
                                             const float* __restrict__ Wf,
                                             const float* __restrict__ bf,
                                             const short* __restrict__ encb,
                                             short* __restrict__ xc2) {
  int b = blockIdx.x;
  __shared__ float a2[1024];
  __shared__ float wfs[1024];
  __shared__ float ee[P_];
  int tid = threadIdx.x;
  for (int i = tid; i < 1024; i += 256) {
    a2[i] = att2p[b * 1024 + i] + att2p[65536 + b * 1024 + i] + bd[i];
    wfs[i] = Wf[i];
  }
  __syncthreads();
  int wave = tid >> 6, lane = tid & 63;
  for (int q = 0; q < 49; ++q) {
    int p = wave + (q << 2);
    const short* a1 = att1 + ((size_t)b * P_ + p) * 1024;
    float s = 0.0f;
#pragma unroll
    for (int h = 0; h < 2; ++h) {
      int k0 = lane * 8 + h * 512;
      bf16x8 v = *(const bf16x8*)(a1 + k0);
#pragma unroll
      for (int j = 0; j < 8; ++j) s += wfs[k0 + j] * fmaxf(b2f(v[j]) + a2[k0 + j], 0.0f);
    }
#pragma unroll
    for (int off = 32; off; off >>= 1) s += __shfl_down(s, off);
    if (lane == 0) ee[p] = s + bf[0];
  }
  __syncthreads();
  if (tid < 64) {
    float vals[4];
    float mx = -1e30f;
#pragma unroll
    for (int q = 0; q < 4; ++q) {
      int p = tid + q * 64;
      vals[q] = (p < P_) ? ee[p] : -1e30f;
      mx = fmaxf(mx, vals[q]);
    }
#pragma unroll
    for (int off = 32; off; off >>= 1) mx = fmaxf(mx, __shfl_xor(mx, off));
    float sum = 0.0f;
#pragma unroll
    for (int q = 0; q < 4; ++q) {
      int p = tid + q * 64;
      vals[q] = (p < P_) ? expf(vals[q] - mx) : 0.0f;
      sum += vals[q];
    }
#pragma unroll
    for (int off = 32; off; off >>= 1) sum += __shfl_xor(sum, off);
    float inv = 1.0f / sum;
#pragma unroll
    for (int q = 0; q < 4; ++q) {
      int p = tid + q * 64;
      if (p < P_) ee[p] = vals[q] * inv;
    }
  }
  __syncthreads();
  int col0 = tid * 8;
  const short* src = encb + (size_t)b * P_ * ENC_ + col0;
  float acc[8] = {};
#pragma unroll 4
  for (int p = 0; p < P_; ++p) {
    bf16x8 v = *(const bf16x8*)(src + (size_t)p * ENC_);
    float ap = ee[p];
#pragma unroll
    for (int j = 0; j < 8; ++j) acc[j] += ap * b2f(v[j]);
  }
#pragma unroll
  for (int j = 0; j < 8; ++j) xc2[b * 4096 + col0 + j] = f2b(acc[j]);
}

// ---------------- head GEMM: out[b, n] = h @ W^T + bias, masked, direct write ----------------
__global__ __launch_bounds__(256) void k_head(const short* __restrict__ A, int lda,
                                              const short* __restrict__ W,
                                              const float* __restrict__ bias,
                                              float* __restrict__ outp,
                                              const int* __restrict__ declen, int t) {
  int wave = threadIdx.x >> 6, lane = threadIdx.x & 63;
  int n0 = blockIdx.x * 64 + wave * 16;  // 157 blocks
  int lr = lane & 15, lk = (lane >> 4) * 8;
  f32x4 acc[4] = {};
  const short* Ab = A + (size_t)lr * lda + lk;
  int nr = n0 + lr;
  bool ok = nr < V_;
  const short* Wb = W + (size_t)(ok ? nr : 0) * 1024 + lk;
  const bf16x8 zv = {0, 0, 0, 0, 0, 0, 0, 0};
  for (int k0 = 0; k0 < 1024; k0 += 32) {
    bf16x8 bfr = ok ? *(const bf16x8*)(Wb + k0) : zv;
#pragma unroll
    for (int i = 0; i < 4; ++i) {
      bf16x8 afr = *(const bf16x8*)(Ab + (size_t)i * 16 * lda + k0);
      acc[i] = __builtin_amdgcn_mfma_f32_16x16x32_bf16(afr, bfr, acc[i], 0, 0, 0);
    }
  }
  int rr = (lane >> 4) * 4, cc = lane & 15;
  int n = n0 + cc;
  if (n < V_) {
    float bn = bias[n];
#pragma unroll
    for (int i = 0; i < 4; ++i) {
#pragma unroll
      for (int r = 0; r < 4; ++r) {
        int b = i * 16 + rr + r;
        float val = acc[i][r] + bn;
        outp[(size_t)b * (TDEC_ * V_) + n] = (t < declen[b]) ? val : 0.0f;
      }
    }
  }
}

// ---------------- host ----------------
extern "C" void kernel_launch(void* const* d_in, const int* in_sizes, int n_in,
                              void* d_out, int out_size, void* d_ws, size_t ws_size,
                              hipStream_t stream) {
  (void)in_sizes; (void)n_in; (void)d_ws; (void)ws_size; (void)out_size;
  const float* enc  = (const float*)d_in[0];
  const int*   caps = (const int*)d_in[1];
  const int*   cl   = (const int*)d_in[2];
  const float* emb  = (const float*)d_in[3];
  const float* We   = (const float*)d_in[4];
  const float* be   = (const float*)d_in[5];
  const float* Wd   = (const float*)d_in[6];
  const float* bd   = (const float*)d_in[7];
  const float* Wf   = (const float*)d_in[8];
  const float* bf   = (const float*)d_in[9];
  const float* Wih1 = (const float*)d_in[10];
  const float* Whh1 = (const float*)d_in[11];
  const float* bih1 = (const float*)d_in[12];
  const float* bhh1 = (const float*)d_in[13];
  const float* Wih2 = (const float*)d_in[14];
  const float* Whh2 = (const float*)d_in[15];
  const float* bih2 = (const float*)d_in[16];
  const float* bhh2 = (const float*)d_in[17];
  const float* Wfc1 = (const float*)d_in[18];
  const float* bfc1 = (const float*)d_in[19];
  const float* Wfc  = (const float*)d_in[20];
  const float* bfc  = (const float*)d_in[21];
  float* out = (float*)d_out;

  short *encb, *att1, *Wc1, *Wc2, *Web, *Wdb, *Wfc1b, *Wfcb, *xc1, *xc2, *em;
  float *part, *att2p, *c1, *c2;
  int* ib;
  hipGetSymbolAddress((void**)&encb, HIP_SYMBOL(g_encb));
  hipGetSymbolAddress((void**)&att1, HIP_SYMBOL(g_att1));
  hipGetSymbolAddress((void**)&Wc1, HIP_SYMBOL(g_Wcat1));
  hipGetSymbolAddress((void**)&Wc2, HIP_SYMBOL(g_Wcat2));
  hipGetSymbolAddress((void**)&Web, HIP_SYMBOL(g_Web));
  hipGetSymbolAddress((void**)&Wdb, HIP_SYMBOL(g_Wdb));
  hipGetSymbolAddress((void**)&Wfc1b, HIP_SYMBOL(g_Wfc1b));
  hipGetSymbolAddress((void**)&Wfcb, HIP_SYMBOL(g_Wfcb));
  hipGetSymbolAddress((void**)&xc1, HIP_SYMBOL(g_xc1));
  hipGetSymbolAddress((void**)&xc2, HIP_SYMBOL(g_xc2));
  hipGetSymbolAddress((void**)&em, HIP_SYMBOL(g_em));
  hipGetSymbolAddress((void**)&part, HIP_SYMBOL(g_part));
  hipGetSymbolAddress((void**)&att2p, HIP_SYMBOL(g_att2p));
  hipGetSymbolAddress((void**)&c1, HIP_SYMBOL(g_c1));
  hipGetSymbolAddress((void**)&c2, HIP_SYMBOL(g_c2));
  hipGetSymbolAddress((void**)&ib, HIP_SYMBOL(g_ibuf));
  int* sind = ib;
  int* declen = ib + 64;
  int* caps_s = ib + 128;

  float* out_preds  = out;
  float* out_preds1 = out + (size_t)B_ * TDEC_ * V_;
  float* out_caps   = out + 2ull * B_ * TDEC_ * V_;
  float* out_declen = out_caps + B_ * MAXLEN_;
  float* out_sind   = out_declen + B_;

  // ---- preprocessing ----
  k_sort<<<1, 64, 0, stream>>>(cl, caps, sind, declen, caps_s, out_caps, out_declen, out_sind);
  hipMemsetAsync(c1, 0, 64 * 1024 * sizeof(float), stream);
  hipMemsetAsync(c2, 0, 64 * 1024 * sizeof(float), stream);
  hipMemsetAsync(xc1, 0, (size_t)64 * 5120 * sizeof(short), stream);  // t=0 buffer
  hipMemsetAsync(xc2, 0, (size_t)64 * 4096 * sizeof(short), stream);
  k_encprep<<<12544, 256, 0, stream>>>(enc, sind, encb);
  k_encmeanb<<<64, 256, 0, stream>>>(encb, em);
  k_prefill<<<dim3(19, 64), 256, 0, stream>>>(emb, caps_s, em, xc1);
  // weight converts (grids = elems/2048)
  k_f2bs<<<8192, 256, 0, stream>>>(Wih1, 4096, Wc1, 5120, 0);
  k_f2bs<<<2048, 256, 0, stream>>>(Whh1, 1024, Wc1, 5120, 4096);
  k_f2bs<<<6144, 256, 0, stream>>>(Wih2, 3072, Wc2, 4096, 0);
  k_f2bs<<<2048, 256, 0, stream>>>(Whh2, 1024, Wc2, 4096, 3072);
  k_f2bs<<<1024, 256, 0, stream>>>(We, 2048, Web, 2048, 0);
  k_f2bs<<<512, 256, 0, stream>>>(Wd, 1024, Wdb, 1024, 0);
  k_f2bs<<<5000, 256, 0, stream>>>(Wfc1, 1024, Wfc1b, 1024, 0);
  k_f2bs<<<5000, 256, 0, stream>>>(Wfc, 1024, Wfcb, 1024, 0);
  k_att1_mfma<<<dim3(98, 4), 512, 0, stream>>>(encb, Web, be, att1);

  // ---- decode loop ----
  for (int t = 0; t < TDEC_; ++t) {
    short* x1t = xc1 + (size_t)t * 64 * 5120;
    short* x1n = xc1 + (size_t)(t + 1) * 64 * 5120;
    // LSTM1: xc1_t[64x5120] @ Wcat1^T   (K=5120, KS=4)
    k_skinny<<<dim3(32, 4), 256, 0, stream>>>(x1t, 5120, Wc1, 5120, 4096, 1280, part);
    k_gates<<<256, 256, 0, stream>>>(part, bih1, bhh1, c1, x1t + 4096, 5120,
                                     x1n + 4096, 5120, xc2 + 2048, 4096, declen, t);
    // att2 = h1 @ Wd^T  (K=1024, KS=2)
    k_skinny<<<dim3(8, 2), 256, 0, stream>>>(xc2 + 2048, 4096, Wdb, 1024, 1024, 512, att2p);
    // fused e + softmax + awe
    k_esa<<<64, 256, 0, stream>>>(att1, att2p, bd, Wf, bf, encb, xc2);
    // preds1 = h1 @ Wfc1^T (direct write)
    k_head<<<157, 256, 0, stream>>>(xc2 + 2048, 4096, Wfc1b, bfc1,
                                    out_preds1 + (size_t)t * V_, declen, t);
    // LSTM2: xc2[64x4096] @ Wcat2^T  (K=4096, KS=4)
    k_skinny<<<dim3(32, 4), 256, 0, stream>>>(xc2, 4096, Wc2, 4096, 4096, 1024, part);
    k_gates<<<256, 256, 0, stream>>>(part, bih2, bhh2, c2, x1t, 5120,
                                     x1n, 5120, xc2 + 3072, 4096, declen, t);
    // preds = h2 @ Wfc^T (direct write)
    k_head<<<157, 256, 0, stream>>>(xc2 + 3072, 4096, Wfcb, bfc,
                                    out_preds + (size_t)t * V_, declen, t);
  }
}

// Round 5
// 3098.228 us; speedup vs baseline: 1.3146x; 1.3146x over previous
//
#include <hip/hip_runtime.h>
#include <cmath>

#define B_ 64
#define P_ 196
#define ENC_ 2048
#define DEC_ 1024
#define V_ 10000
#define MAXLEN_ 20
#define TDEC_ 19

typedef __attribute__((ext_vector_type(8))) short bf16x8;
typedef __attribute__((ext_vector_type(4))) float f32x4;

// Tiled weight layout: tile = 16 rows x 32 k = 512 bf16 = 1KB, k-tiles fastest.
// element (r,k): offset = ((r>>4)*(K>>5) + (k>>5))*512 + ((r&15) | (((k>>3)&3)<<4))*8 + (k&7)
// => a wave's MFMA B-fragment (16 rows x 32 k) is ONE contiguous 1KB block, lane l at l*16B.

// ---------------- static device buffers ----------------
__device__ __align__(16) short g_encb[(size_t)12544 * 2048];    // sorted enc, bf16 row-major (for awe)
__device__ __align__(16) short g_encbt[(size_t)12544 * 2048];   // sorted enc, bf16 TILED (for att1)
__device__ __align__(16) short g_att1[(size_t)12544 * 1024];    // att1, bf16 row-major (incl. be)
__device__ __align__(16) short g_Wc1t[(size_t)4096 * 5120];     // [Wih1(4096)|Whh1(1024)] tiled
__device__ __align__(16) short g_Wc2t[(size_t)4096 * 4096];     // [Wih2(3072)|Whh2(1024)] tiled
__device__ __align__(16) short g_Webt[(size_t)1024 * 2048];     // We tiled
__device__ __align__(16) short g_Wdt[(size_t)1024 * 1024];      // Wd tiled
__device__ __align__(16) short g_Wfc1t[(size_t)10000 * 1024];   // Wfc1 tiled
__device__ __align__(16) short g_Wfct[(size_t)10000 * 1024];    // Wfc tiled
__device__ __align__(16) short g_xc1[(size_t)20 * 64 * 5120];   // per-t [h2|em|emb_t|h1]
__device__ __align__(16) short g_xc2[64 * 4096];                // [awe | h1 | h2]
__device__ __align__(16) short g_em[64 * 2048];                 // enc mean, bf16
__device__ __align__(16) float g_part[(size_t)4 * 64 * 4096];
__device__ __align__(16) float g_att2p[2 * 64 * 1024];
__device__ __align__(16) float g_e[64 * P_];
__device__ __align__(16) float g_c1[64 * 1024];
__device__ __align__(16) float g_c2[64 * 1024];
__device__ int g_ibuf[64 + 64 + 64 * MAXLEN_];

__device__ __forceinline__ short f2b(float f) {
  unsigned u = __float_as_uint(f);
  u += 0x7FFFu + ((u >> 16) & 1u);
  return (short)(u >> 16);
}
__device__ __forceinline__ float b2f(short s) {
  return __uint_as_float(((unsigned)(unsigned short)s) << 16);
}

// ---------------- sort + int-ish outputs ----------------
__global__ void k_sort(const int* __restrict__ cl_in, const int* __restrict__ caps_in,
                       int* __restrict__ sind, int* __restrict__ declen, int* __restrict__ caps_s,
                       float* __restrict__ out_caps, float* __restrict__ out_declen,
                       float* __restrict__ out_sind) {
  int i = threadIdx.x;  // 64 threads
  __shared__ int cl[B_];
  cl[i] = cl_in[i];
  __syncthreads();
  int my = cl[i], pos = 0;
  for (int j = 0; j < B_; ++j) {
    int cj = cl[j];
    if (cj > my || (cj == my && j < i)) pos++;
  }
  sind[pos] = i;
  __syncthreads();
  int sb = sind[i];
  int dl = cl[sb] - 1;
  declen[i] = dl;
  out_declen[i] = (float)dl;
  out_sind[i] = (float)sb;
  for (int t = 0; t < MAXLEN_; ++t) {
    int v = caps_in[sb * MAXLEN_ + t];
    caps_s[i * MAXLEN_ + t] = v;
    out_caps[i * MAXLEN_ + t] = (float)v;
  }
}

// gather-sort + fp32->bf16 encoder: writes row-major AND tiled copies
__global__ __launch_bounds__(256) void k_encprep(const float* __restrict__ enc,
                                                 const int* __restrict__ sind,
                                                 short* __restrict__ encb,
                                                 short* __restrict__ encbt) {
  int mg = blockIdx.x;  // 12544
  int b = mg / P_, p = mg - b * P_;
  int tid = threadIdx.x;
  const float* src = enc + ((size_t)sind[b] * P_ + p) * ENC_ + tid * 8;
  float4 a = *(const float4*)src;
  float4 c = *(const float4*)(src + 4);
  bf16x8 v;
  v[0] = f2b(a.x); v[1] = f2b(a.y); v[2] = f2b(a.z); v[3] = f2b(a.w);
  v[4] = f2b(c.x); v[5] = f2b(c.y); v[6] = f2b(c.z); v[7] = f2b(c.w);
  *(bf16x8*)(encb + (size_t)mg * ENC_ + tid * 8) = v;
  size_t off = (((size_t)(mg >> 4) * 64 + (tid >> 2)) << 9) +
               (((mg & 15) | ((tid & 3) << 4)) << 3);
  *(bf16x8*)(encbt + off) = v;
}

// enc mean (over bf16 enc) -> g_em (bf16)
__global__ __launch_bounds__(256) void k_encmeanb(const short* __restrict__ encb,
                                                  short* __restrict__ em) {
  int b = blockIdx.x;
  int col0 = threadIdx.x * 8;
  const short* src = encb + (size_t)b * P_ * ENC_ + col0;
  float acc[8] = {};
  for (int p = 0; p < P_; ++p) {
    bf16x8 v = *(const bf16x8*)(src + (size_t)p * ENC_);
#pragma unroll
    for (int j = 0; j < 8; ++j) acc[j] += b2f(v[j]);
  }
#pragma unroll
  for (int j = 0; j < 8; ++j) em[b * 2048 + col0 + j] = f2b(acc[j] * (1.0f / 196.0f));
}

// prefill em + emb slots of every per-t xc1 buffer
__global__ __launch_bounds__(256) void k_prefill(const float* __restrict__ emb,
                                                 const int* __restrict__ caps_s,
                                                 const short* __restrict__ em,
                                                 short* __restrict__ xc1all) {
  int t = blockIdx.x, b = blockIdx.y, tid = threadIdx.x;  // (19, 64)
  short* xr = xc1all + ((size_t)t * 64 + b) * 5120;
  int i = tid * 8;
  *(bf16x8*)(xr + 1024 + i) = *(const bf16x8*)(em + b * 2048 + i);
  int cap = caps_s[b * MAXLEN_ + t];
  int j = tid * 4;
  float4 v = *(const float4*)(emb + (size_t)cap * 1024 + j);
  short4 o;
  o.x = f2b(v.x); o.y = f2b(v.y); o.z = f2b(v.z); o.w = f2b(v.w);
  *(short4*)(xr + 3072 + j) = o;
}

// fp32 row-major [N x Ksrc] -> bf16 TILED dst with total K = Ktot, k-offset koff
__global__ void k_f2bt(const float* __restrict__ src, int Ksrc, short* __restrict__ dst,
                       int Ktot, int koff) {
  int idx = blockIdx.x * 256 + threadIdx.x;  // one per 8 elems
  int kc = Ksrc >> 3;
  int r = idx / kc, k8 = (idx - r * kc) << 3;
  const float* s = src + (size_t)r * Ksrc + k8;
  float4 a = *(const float4*)s;
  float4 c = *(const float4*)(s + 4);
  bf16x8 v;
  v[0] = f2b(a.x); v[1] = f2b(a.y); v[2] = f2b(a.z); v[3] = f2b(a.w);
  v[4] = f2b(c.x); v[5] = f2b(c.y); v[6] = f2b(c.z); v[7] = f2b(c.w);
  int kg = koff + k8;
  size_t off = (((size_t)(r >> 4) * (Ktot >> 5) + (kg >> 5)) << 9) +
               (((r & 15) | (((kg >> 3) & 3) << 4)) << 3);
  *(bf16x8*)(dst + off) = v;
}

// ---------------- att1 = enc @ We^T + be -> bf16 (12544x1024, K=2048), both TILED ----------------
__global__ __launch_bounds__(512) void k_att1_t(const short* __restrict__ At,
                                                const short* __restrict__ Wt,
                                                const float* __restrict__ be,
                                                short* __restrict__ Cb) {
  int wave = threadIdx.x >> 6, lane = threadIdx.x & 63;
  int mt0 = blockIdx.x * 8 + (wave >> 2) * 4;   // 4 m-tiles (64 rows) per wave
  int nt0 = blockIdx.y * 16 + (wave & 3) * 4;   // 4 n-tiles (64 cols) per wave
  f32x4 acc[4][4] = {};
  const short* Ab = At + ((size_t)mt0 * 64 << 9) + lane * 8;  // ntk = 2048/32 = 64
  const short* Wb = Wt + ((size_t)nt0 * 64 << 9) + lane * 8;
  for (int kt = 0; kt < 64; ++kt) {
    bf16x8 a[4], b[4];
#pragma unroll
    for (int i = 0; i < 4; ++i) a[i] = *(const bf16x8*)(Ab + (((size_t)i * 64 + kt) << 9));
#pragma unroll
    for (int j = 0; j < 4; ++j) b[j] = *(const bf16x8*)(Wb + (((size_t)j * 64 + kt) << 9));
#pragma unroll
    for (int i = 0; i < 4; ++i)
#pragma unroll
      for (int j = 0; j < 4; ++j)
        acc[i][j] = __builtin_amdgcn_mfma_f32_16x16x32_bf16(a[i], b[j], acc[i][j], 0, 0, 0);
  }
  int rr = (lane >> 4) * 4, cc = lane & 15;
  int m0 = mt0 * 16, n0 = nt0 * 16;
#pragma unroll
  for (int i = 0; i < 4; ++i)
#pragma unroll
    for (int j = 0; j < 4; ++j) {
      int n = n0 + j * 16 + cc;
      float bn = be[n];
#pragma unroll
      for (int r = 0; r < 4; ++r) {
        int m = m0 + i * 16 + rr + r;
        Cb[(size_t)m * 1024 + n] = f2b(acc[i][j][r] + bn);
      }
    }
}

// ---------------- skinny MFMA GEMM, tiled W: part[s][64][N] = A[64xK] @ W[NxK]^T chunk ----------------
__global__ __launch_bounds__(256) void k_skinny_t(const short* __restrict__ A, int lda,
                                                  const short* __restrict__ Wt, int ldw,
                                                  int N, int kchunk, float* __restrict__ part) {
  int wave = threadIdx.x >> 6, lane = threadIdx.x & 63;
  int n0 = blockIdx.x * 128 + wave * 32;
  int kb = blockIdx.y * kchunk;
  int lr = lane & 15, lk = (lane >> 4) * 8;
  int ntk = ldw >> 5, ntN = N >> 4;
  int nt0 = n0 >> 4;
  bool ok0 = nt0 < ntN, ok1 = nt0 + 1 < ntN;
  f32x4 acc[4][2] = {};
  const short* Ab = A + (size_t)lr * lda + kb + lk;
  const short* Wb0 = Wt + (((size_t)(ok0 ? nt0 : 0) * ntk + (kb >> 5)) << 9) + lane * 8;
  const short* Wb1 = Wt + (((size_t)(ok1 ? nt0 + 1 : 0) * ntk + (kb >> 5)) << 9) + lane * 8;
  const bf16x8 zv = {0, 0, 0, 0, 0, 0, 0, 0};
  int nkt = kchunk >> 5;
  for (int kt = 0; kt < nkt; ++kt) {
    bf16x8 a[4], b0, b1;
#pragma unroll
    for (int i = 0; i < 4; ++i) a[i] = *(const bf16x8*)(Ab + (size_t)i * 16 * lda + kt * 32);
    b0 = ok0 ? *(const bf16x8*)(Wb0 + ((size_t)kt << 9)) : zv;
    b1 = ok1 ? *(const bf16x8*)(Wb1 + ((size_t)kt << 9)) : zv;
#pragma unroll
    for (int i = 0; i < 4; ++i) {
      acc[i][0] = __builtin_amdgcn_mfma_f32_16x16x32_bf16(a[i], b0, acc[i][0], 0, 0, 0);
      acc[i][1] = __builtin_amdgcn_mfma_f32_16x16x32_bf16(a[i], b1, acc[i][1], 0, 0, 0);
    }
  }
  float* po = part + (size_t)blockIdx.y * 64 * N;
  int rr = (lane >> 4) * 4, cc = lane & 15;
#pragma unroll
  for (int i = 0; i < 4; ++i)
#pragma unroll
    for (int j = 0; j < 2; ++j) {
      int n = n0 + j * 16 + cc;
      if (n < N) {
#pragma unroll
        for (int r = 0; r < 4; ++r) {
          int m = i * 16 + rr + r;
          po[(size_t)m * N + n] = acc[i][j][r];
        }
      }
    }
}

// ---------------- LSTM gates: sum 4 partials + biases, update c, forward h (bf16) ----------------
__global__ void k_gates(const float* __restrict__ part, const float* __restrict__ bih,
                        const float* __restrict__ bhh, float* __restrict__ c,
                        const short* __restrict__ hold, int ldo,
                        short* __restrict__ dst1, int ld1,
                        short* __restrict__ dst2, int ld2,
                        const int* __restrict__ declen, int t) {
  int idx = blockIdx.x * 256 + threadIdx.x;  // 65536
  int b = idx >> 10, j = idx & 1023;
  const float* pb = part + (size_t)b * 4096;
  float gi = bih[j] + bhh[j];
  float gf = bih[1024 + j] + bhh[1024 + j];
  float gg = bih[2048 + j] + bhh[2048 + j];
  float go = bih[3072 + j] + bhh[3072 + j];
#pragma unroll
  for (int s = 0; s < 4; ++s) {
    const float* p = pb + (size_t)s * 64 * 4096;
    gi += p[j]; gf += p[j + 1024]; gg += p[j + 2048]; go += p[j + 3072];
  }
  float si = 1.0f / (1.0f + expf(-gi));
  float sf = 1.0f / (1.0f + expf(-gf));
  float so = 1.0f / (1.0f + expf(-go));
  float cn = sf * c[idx] + si * tanhf(gg);
  float hn = so * tanhf(cn);
  short hb;
  if (t < declen[b]) {
    c[idx] = cn;
    hb = f2b(hn);
  } else {
    hb = hold[b * ldo + j];
  }
  dst1[b * ld1 + j] = hb;
  dst2[b * ld2 + j] = hb;
}

// ---------------- e[b,p] = Wf . relu(att1[b,p,:] + att2) + bf (3136 blocks) ----------------
__global__ __launch_bounds__(256) void k_e(const short* __restrict__ att1,
                                           const float* __restrict__ att2p,
                                           const float* __restrict__ bd,
                                           const float* __restrict__ Wf,
                                           const float* __restrict__ bf,
                                           float* __restrict__ e) {
  __shared__ float a2[1024];
  int b = blockIdx.x / 49, pq = blockIdx.x % 49;
  for (int i = threadIdx.x; i < 1024; i += 256)
    a2[i] = att2p[b * 1024 + i] + att2p[65536 + b * 1024 + i] + bd[i];
  __syncthreads();
  int wave = threadIdx.x >> 6, lane = threadIdx.x & 63;
  int p = pq * 4 + wave;
  const short* a1 = att1 + ((size_t)(b * P_ + p)) * 1024;
  float s = 0.0f;
#pragma unroll
  for (int h = 0; h < 2; ++h) {
    int k0 = lane * 8 + h * 512;
    bf16x8 v = *(const bf16x8*)(a1 + k0);
#pragma unroll
    for (int j = 0; j < 8; ++j) s += Wf[k0 + j] * fmaxf(b2f(v[j]) + a2[k0 + j], 0.0f);
  }
#pragma unroll
  for (int off = 32; off; off >>= 1) s += __shfl_down(s, off);
  if (lane == 0) e[b * P_ + p] = s + bf[0];
}

// ---------------- softmax (in-block) + awe, parallel over (b, 8 col-chunks) ----------------
__global__ __launch_bounds__(256) void k_sawe(const float* __restrict__ e,
                                              const short* __restrict__ encb,
                                              short* __restrict__ xc2) {
  int b = blockIdx.x, ch = blockIdx.y;  // ch < 8, 256 cols each
  __shared__ float al[P_];
  __shared__ float red[8][256];
  int tid = threadIdx.x;
  if (tid < 64) {
    float vals[4];
    float mx = -1e30f;
#pragma unroll
    for (int q = 0; q < 4; ++q) {
      int p = tid + q * 64;
      vals[q] = (p < P_) ? e[b * P_ + p] : -1e30f;
      mx = fmaxf(mx, vals[q]);
    }
#pragma unroll
    for (int off = 32; off; off >>= 1) mx = fmaxf(mx, __shfl_xor(mx, off));
    float sum = 0.0f;
#pragma unroll
    for (int q = 0; q < 4; ++q) {
      int p = tid + q * 64;
      vals[q] = (p < P_) ? expf(vals[q] - mx) : 0.0f;
      sum += vals[q];
    }
#pragma unroll
    for (int off = 32; off; off >>= 1) sum += __shfl_xor(sum, off);
    float inv = 1.0f / sum;
#pragma unroll
    for (int q = 0; q < 4; ++q) {
      int p = tid + q * 64;
      if (p < P_) al[p] = vals[q] * inv;
    }
  }
  __syncthreads();
  int pg = tid >> 5, cg = tid & 31;
  int col = ch * 256 + cg * 8;
  const short* src = encb + (size_t)b * P_ * ENC_ + col;
  float acc[8] = {};
  for (int p = pg; p < P_; p += 8) {
    bf16x8 v = *(const bf16x8*)(src + (size_t)p * ENC_);
    float ap = al[p];
#pragma unroll
    for (int j = 0; j < 8; ++j) acc[j] += ap * b2f(v[j]);
  }
#pragma unroll
  for (int j = 0; j < 8; ++j) red[pg][cg * 8 + j] = acc[j];
  __syncthreads();
  float s = 0.0f;
#pragma unroll
  for (int g = 0; g < 8; ++g) s += red[g][tid];
  xc2[b * 4096 + ch * 256 + tid] = f2b(s);
}

// ---------------- head GEMM (tiled W): out = h @ W^T + bias, masked, direct write ----------------
__global__ __launch_bounds__(256) void k_head_t(const short* __restrict__ A, int lda,
                                                const short* __restrict__ Wt,
                                                const float* __restrict__ bias,
                                                float* __restrict__ outp,
                                                const int* __restrict__ declen, int t) {
  int wave = threadIdx.x >> 6, lane = threadIdx.x & 63;
  int nt = blockIdx.x * 4 + wave;  // n-tile; 157 blocks -> nt in [0, 628)
  bool ok = nt < (V_ >> 4);        // 625 tiles
  int lr = lane & 15, lk = (lane >> 4) * 8;
  f32x4 acc[4] = {};
  const short* Ab = A + (size_t)lr * lda + lk;
  const short* Wb = Wt + ((size_t)(ok ? nt : 0) * 32 << 9) + lane * 8;  // ntk = 32
  const bf16x8 zv = {0, 0, 0, 0, 0, 0, 0, 0};
  for (int kt = 0; kt < 32; ++kt) {
    bf16x8 bfr = ok ? *(const bf16x8*)(Wb + ((size_t)kt << 9)) : zv;
#pragma unroll
    for (int i = 0; i < 4; ++i) {
      bf16x8 afr = *(const bf16x8*)(Ab + (size_t)i * 16 * lda + kt * 32);
      acc[i] = __builtin_amdgcn_mfma_f32_16x16x32_bf16(afr, bfr, acc[i], 0, 0, 0);
    }
  }
  int rr = (lane >> 4) * 4, cc = lane & 15;
  int n = nt * 16 + cc;
  if (n < V_) {
    float bn = bias[n];
#pragma unroll
    for (int i = 0; i < 4; ++i) {
#pragma unroll
      for (int r = 0; r < 4; ++r) {
        int b = i * 16 + rr + r;
        float val = acc[i][r] + bn;
        outp[(size_t)b * (TDEC_ * V_) + n] = (t < declen[b]) ? val : 0.0f;
      }
    }
  }
}

// ---------------- host ----------------
extern "C" void kernel_launch(void* const* d_in, const int* in_sizes, int n_in,
                              void* d_out, int out_size, void* d_ws, size_t ws_size,
                              hipStream_t stream) {
  (void)in_sizes; (void)n_in; (void)d_ws; (void)ws_size; (void)out_size;
  const float* enc  = (const float*)d_in[0];
  const int*   caps = (const int*)d_in[1];
  const int*   cl   = (const int*)d_in[2];
  const float* emb  = (const float*)d_in[3];
  const float* We   = (const float*)d_in[4];
  const float* be   = (const float*)d_in[5];
  const float* Wd   = (const float*)d_in[6];
  const float* bd   = (const float*)d_in[7];
  const float* Wf   = (const float*)d_in[8];
  const float* bf   = (const float*)d_in[9];
  const float* Wih1 = (const float*)d_in[10];
  const float* Whh1 = (const float*)d_in[11];
  const float* bih1 = (const float*)d_in[12];
  const float* bhh1 = (const float*)d_in[13];
  const float* Wih2 = (const float*)d_in[14];
  const float* Whh2 = (const float*)d_in[15];
  const float* bih2 = (const float*)d_in[16];
  const float* bhh2 = (const float*)d_in[17];
  const float* Wfc1 = (const float*)d_in[18];
  const float* bfc1 = (const float*)d_in[19];
  const float* Wfc  = (const float*)d_in[20];
  const float* bfc  = (const float*)d_in[21];
  float* out = (float*)d_out;

  short *encb, *encbt, *att1, *Wc1t, *Wc2t, *Webt, *Wdt, *Wfc1t, *Wfct, *xc1, *xc2, *em;
  float *part, *att2p, *e, *c1, *c2;
  int* ib;
  hipGetSymbolAddress((void**)&encb, HIP_SYMBOL(g_encb));
  hipGetSymbolAddress((void**)&encbt, HIP_SYMBOL(g_encbt));
  hipGetSymbolAddress((void**)&att1, HIP_SYMBOL(g_att1));
  hipGetSymbolAddress((void**)&Wc1t, HIP_SYMBOL(g_Wc1t));
  hipGetSymbolAddress((void**)&Wc2t, HIP_SYMBOL(g_Wc2t));
  hipGetSymbolAddress((void**)&Webt, HIP_SYMBOL(g_Webt));
  hipGetSymbolAddress((void**)&Wdt, HIP_SYMBOL(g_Wdt));
  hipGetSymbolAddress((void**)&Wfc1t, HIP_SYMBOL(g_Wfc1t));
  hipGetSymbolAddress((void**)&Wfct, HIP_SYMBOL(g_Wfct));
  hipGetSymbolAddress((void**)&xc1, HIP_SYMBOL(g_xc1));
  hipGetSymbolAddress((void**)&xc2, HIP_SYMBOL(g_xc2));
  hipGetSymbolAddress((void**)&em, HIP_SYMBOL(g_em));
  hipGetSymbolAddress((void**)&part, HIP_SYMBOL(g_part));
  hipGetSymbolAddress((void**)&att2p, HIP_SYMBOL(g_att2p));
  hipGetSymbolAddress((void**)&e, HIP_SYMBOL(g_e));
  hipGetSymbolAddress((void**)&c1, HIP_SYMBOL(g_c1));
  hipGetSymbolAddress((void**)&c2, HIP_SYMBOL(g_c2));
  hipGetSymbolAddress((void**)&ib, HIP_SYMBOL(g_ibuf));
  int* sind = ib;
  int* declen = ib + 64;
  int* caps_s = ib + 128;

  float* out_preds  = out;
  float* out_preds1 = out + (size_t)B_ * TDEC_ * V_;
  float* out_caps   = out + 2ull * B_ * TDEC_ * V_;
  float* out_declen = out_caps + B_ * MAXLEN_;
  float* out_sind   = out_declen + B_;

  // ---- preprocessing ----
  k_sort<<<1, 64, 0, stream>>>(cl, caps, sind, declen, caps_s, out_caps, out_declen, out_sind);
  hipMemsetAsync(c1, 0, 64 * 1024 * sizeof(float), stream);
  hipMemsetAsync(c2, 0, 64 * 1024 * sizeof(float), stream);
  hipMemsetAsync(xc1, 0, (size_t)64 * 5120 * sizeof(short), stream);  // t=0 buffer
  hipMemsetAsync(xc2, 0, (size_t)64 * 4096 * sizeof(short), stream);
  k_encprep<<<12544, 256, 0, stream>>>(enc, sind, encb, encbt);
  k_encmeanb<<<64, 256, 0, stream>>>(encb, em);
  k_prefill<<<dim3(19, 64), 256, 0, stream>>>(emb, caps_s, em, xc1);
  // tiled weight converts (grid = N*K/2048)
  k_f2bt<<<8192, 256, 0, stream>>>(Wih1, 4096, Wc1t, 5120, 0);
  k_f2bt<<<2048, 256, 0, stream>>>(Whh1, 1024, Wc1t, 5120, 4096);
  k_f2bt<<<6144, 256, 0, stream>>>(Wih2, 3072, Wc2t, 4096, 0);
  k_f2bt<<<2048, 256, 0, stream>>>(Whh2, 1024, Wc2t, 4096, 3072);
  k_f2bt<<<1024, 256, 0, stream>>>(We, 2048, Webt, 2048, 0);
  k_f2bt<<<512, 256, 0, stream>>>(Wd, 1024, Wdt, 1024, 0);
  k_f2bt<<<5000, 256, 0, stream>>>(Wfc1, 1024, Wfc1t, 1024, 0);
  k_f2bt<<<5000, 256, 0, stream>>>(Wfc, 1024, Wfct, 1024, 0);
  k_att1_t<<<dim3(98, 4), 512, 0, stream>>>(encbt, Webt, be, att1);

  // ---- decode loop ----
  for (int t = 0; t < TDEC_; ++t) {
    short* x1t = xc1 + (size_t)t * 64 * 5120;
    short* x1n = xc1 + (size_t)(t + 1) * 64 * 5120;
    // LSTM1: xc1_t[64x5120] @ Wcat1^T   (K=5120, KS=4)
    k_skinny_t<<<dim3(32, 4), 256, 0, stream>>>(x1t, 5120, Wc1t, 5120, 4096, 1280, part);
    k_gates<<<256, 256, 0, stream>>>(part, bih1, bhh1, c1, x1t + 4096, 5120,
                                     x1n + 4096, 5120, xc2 + 2048, 4096, declen, t);
    // att2 = h1 @ Wd^T  (K=1024, KS=2)
    k_skinny_t<<<dim3(8, 2), 256, 0, stream>>>(xc2 + 2048, 4096, Wdt, 1024, 1024, 512, att2p);
    k_e<<<3136, 256, 0, stream>>>(att1, att2p, bd, Wf, bf, e);
    k_sawe<<<dim3(64, 8), 256, 0, stream>>>(e, encb, xc2);
    // preds1 = h1 @ Wfc1^T (direct write)
    k_head_t<<<157, 256, 0, stream>>>(xc2 + 2048, 4096, Wfc1t, bfc1,
                                      out_preds1 + (size_t)t * V_, declen, t);
    // LSTM2: xc2[64x4096] @ Wcat2^T  (K=4096, KS=4)
    k_skinny_t<<<dim3(32, 4), 256, 0, stream>>>(xc2, 4096, Wc2t, 4096, 4096, 1024, part);
    k_gates<<<256, 256, 0, stream>>>(part, bih2, bhh2, c2, x1t, 5120,
                                     x1n, 5120, xc2 + 3072, 4096, declen, t);
    // preds = h2 @ Wfc^T (direct write)
    k_head_t<<<157, 256, 0, stream>>>(xc2 + 3072, 4096, Wfct, bfc,
                                      out_preds + (size_t)t * V_, declen, t);
  }
}

// Round 6
// 2158.098 us; speedup vs baseline: 1.8872x; 1.4356x over previous
//
#include <hip/hip_runtime.h>
#include <cmath>

#define B_ 64
#define P_ 196
#define ENC_ 2048
#define DEC_ 1024
#define V_ 10000
#define MAXLEN_ 20
#define TDEC_ 19

typedef __attribute__((ext_vector_type(8))) short bf16x8;
typedef __attribute__((ext_vector_type(4))) float f32x4;

// Tiled weight layout: tile = 16 rows x 32 k = 512 bf16 = 1KB, k-tiles fastest.
// element (r,k): offset = ((r>>4)*(K>>5) + (k>>5))*512 + ((r&15) | (((k>>3)&3)<<4))*8 + (k&7)

// ---------------- static device buffers ----------------
__device__ __align__(16) short g_encb[(size_t)12544 * 2048];    // sorted enc, bf16 row-major
__device__ __align__(16) short g_encbt[(size_t)12544 * 2048];   // sorted enc, bf16 TILED
__device__ __align__(16) short g_att1[(size_t)12544 * 1024];    // att1, bf16 (incl. be)
__device__ __align__(16) short g_Wc1t[(size_t)4096 * 5120];     // [Wih1(4096)|Whh1(1024)] tiled
__device__ __align__(16) short g_Wc2t[(size_t)4096 * 4096];     // [Wih2(3072)|Whh2(1024)] tiled
__device__ __align__(16) short g_Webt[(size_t)1024 * 2048];     // We tiled
__device__ __align__(16) short g_Wdt[(size_t)1024 * 1024];      // Wd tiled
__device__ __align__(16) short g_Wfc1t[(size_t)10000 * 1024];   // Wfc1 tiled
__device__ __align__(16) short g_Wfct[(size_t)10000 * 1024];    // Wfc tiled
__device__ __align__(16) short g_xc1[(size_t)20 * 64 * 5120];   // per-t [h2|em|emb_t|h1]
__device__ __align__(16) short g_xc2[(size_t)20 * 64 * 4096];   // per-t [awe|h1|h2]
__device__ __align__(16) short g_em[64 * 2048];                 // enc mean, bf16
__device__ __align__(16) float g_part[(size_t)8 * 64 * 4096];
__device__ __align__(16) float g_att2p[(size_t)4 * 64 * 1024];
__device__ __align__(16) float g_e[64 * P_];
__device__ __align__(16) float g_c1[64 * 1024];
__device__ __align__(16) float g_c2[64 * 1024];
__device__ int g_ibuf[64 + 64 + 64 * MAXLEN_];

__device__ __forceinline__ short f2b(float f) {
  unsigned u = __float_as_uint(f);
  u += 0x7FFFu + ((u >> 16) & 1u);
  return (short)(u >> 16);
}
__device__ __forceinline__ float b2f(short s) {
  return __uint_as_float(((unsigned)(unsigned short)s) << 16);
}

// ---------------- sort + int-ish outputs ----------------
__global__ void k_sort(const int* __restrict__ cl_in, const int* __restrict__ caps_in,
                       int* __restrict__ sind, int* __restrict__ declen, int* __restrict__ caps_s,
                       float* __restrict__ out_caps, float* __restrict__ out_declen,
                       float* __restrict__ out_sind) {
  int i = threadIdx.x;  // 64 threads
  __shared__ int cl[B_];
  cl[i] = cl_in[i];
  __syncthreads();
  int my = cl[i], pos = 0;
  for (int j = 0; j < B_; ++j) {
    int cj = cl[j];
    if (cj > my || (cj == my && j < i)) pos++;
  }
  sind[pos] = i;
  __syncthreads();
  int sb = sind[i];
  int dl = cl[sb] - 1;
  declen[i] = dl;
  out_declen[i] = (float)dl;
  out_sind[i] = (float)sb;
  for (int t = 0; t < MAXLEN_; ++t) {
    int v = caps_in[sb * MAXLEN_ + t];
    caps_s[i * MAXLEN_ + t] = v;
    out_caps[i * MAXLEN_ + t] = (float)v;
  }
}

// gather-sort + fp32->bf16 encoder: row-major AND tiled copies
__global__ __launch_bounds__(256) void k_encprep(const float* __restrict__ enc,
                                                 const int* __restrict__ sind,
                                                 short* __restrict__ encb,
                                                 short* __restrict__ encbt) {
  int mg = blockIdx.x;  // 12544
  int b = mg / P_, p = mg - b * P_;
  int tid = threadIdx.x;
  const float* src = enc + ((size_t)sind[b] * P_ + p) * ENC_ + tid * 8;
  float4 a = *(const float4*)src;
  float4 c = *(const float4*)(src + 4);
  bf16x8 v;
  v[0] = f2b(a.x); v[1] = f2b(a.y); v[2] = f2b(a.z); v[3] = f2b(a.w);
  v[4] = f2b(c.x); v[5] = f2b(c.y); v[6] = f2b(c.z); v[7] = f2b(c.w);
  *(bf16x8*)(encb + (size_t)mg * ENC_ + tid * 8) = v;
  size_t off = (((size_t)(mg >> 4) * 64 + (tid >> 2)) << 9) +
               (((mg & 15) | ((tid & 3) << 4)) << 3);
  *(bf16x8*)(encbt + off) = v;
}

// enc mean -> g_em (bf16)
__global__ __launch_bounds__(256) void k_encmeanb(const short* __restrict__ encb,
                                                  short* __restrict__ em) {
  int b = blockIdx.x;
  int col0 = threadIdx.x * 8;
  const short* src = encb + (size_t)b * P_ * ENC_ + col0;
  float acc[8] = {};
  for (int p = 0; p < P_; ++p) {
    bf16x8 v = *(const bf16x8*)(src + (size_t)p * ENC_);
#pragma unroll
    for (int j = 0; j < 8; ++j) acc[j] += b2f(v[j]);
  }
#pragma unroll
  for (int j = 0; j < 8; ++j) em[b * 2048 + col0 + j] = f2b(acc[j] * (1.0f / 196.0f));
}

// prefill em + emb slots of every per-t xc1 buffer
__global__ __launch_bounds__(256) void k_prefill(const float* __restrict__ emb,
                                                 const int* __restrict__ caps_s,
                                                 const short* __restrict__ em,
                                                 short* __restrict__ xc1all) {
  int t = blockIdx.x, b = blockIdx.y, tid = threadIdx.x;  // (19, 64)
  short* xr = xc1all + ((size_t)t * 64 + b) * 5120;
  int i = tid * 8;
  *(bf16x8*)(xr + 1024 + i) = *(const bf16x8*)(em + b * 2048 + i);
  int cap = caps_s[b * MAXLEN_ + t];
  int j = tid * 4;
  float4 v = *(const float4*)(emb + (size_t)cap * 1024 + j);
  short4 o;
  o.x = f2b(v.x); o.y = f2b(v.y); o.z = f2b(v.z); o.w = f2b(v.w);
  *(short4*)(xr + 3072 + j) = o;
}

// fp32 row-major [N x Ksrc] -> bf16 TILED dst, total K = Ktot, k-offset koff
__global__ void k_f2bt(const float* __restrict__ src, int Ksrc, short* __restrict__ dst,
                       int Ktot, int koff) {
  int idx = blockIdx.x * 256 + threadIdx.x;
  int kc = Ksrc >> 3;
  int r = idx / kc, k8 = (idx - r * kc) << 3;
  const float* s = src + (size_t)r * Ksrc + k8;
  float4 a = *(const float4*)s;
  float4 c = *(const float4*)(s + 4);
  bf16x8 v;
  v[0] = f2b(a.x); v[1] = f2b(a.y); v[2] = f2b(a.z); v[3] = f2b(a.w);
  v[4] = f2b(c.x); v[5] = f2b(c.y); v[6] = f2b(c.z); v[7] = f2b(c.w);
  int kg = koff + k8;
  size_t off = (((size_t)(r >> 4) * (Ktot >> 5) + (kg >> 5)) << 9) +
               (((r & 15) | (((kg >> 3) & 3) << 4)) << 3);
  *(bf16x8*)(dst + off) = v;
}

// ---------------- att1 = enc @ We^T + be -> bf16 (12544x1024), both TILED ----------------
// 1024 threads: 16 waves = 2 m-groups x 8 n-groups; block = 128 rows x 512 cols
__global__ __launch_bounds__(1024) void k_att1_t(const short* __restrict__ At,
                                                 const short* __restrict__ Wt,
                                                 const float* __restrict__ be,
                                                 short* __restrict__ Cb) {
  int wave = threadIdx.x >> 6, lane = threadIdx.x & 63;
  int mt0 = blockIdx.x * 8 + (wave >> 3) * 4;
  int nt0 = blockIdx.y * 32 + (wave & 7) * 4;
  f32x4 acc[4][4] = {};
  const short* Ab = At + ((size_t)mt0 * 64 << 9) + lane * 8;  // 64 k-tiles
  const short* Wb = Wt + ((size_t)nt0 * 64 << 9) + lane * 8;
  for (int kt = 0; kt < 64; ++kt) {
    bf16x8 a[4], b[4];
#pragma unroll
    for (int i = 0; i < 4; ++i) a[i] = *(const bf16x8*)(Ab + (((size_t)i * 64 + kt) << 9));
#pragma unroll
    for (int j = 0; j < 4; ++j) b[j] = *(const bf16x8*)(Wb + (((size_t)j * 64 + kt) << 9));
#pragma unroll
    for (int i = 0; i < 4; ++i)
#pragma unroll
      for (int j = 0; j < 4; ++j)
        acc[i][j] = __builtin_amdgcn_mfma_f32_16x16x32_bf16(a[i], b[j], acc[i][j], 0, 0, 0);
  }
  int rr = (lane >> 4) * 4, cc = lane & 15;
  int m0 = mt0 * 16, n0 = nt0 * 16;
#pragma unroll
  for (int i = 0; i < 4; ++i)
#pragma unroll
    for (int j = 0; j < 4; ++j) {
      int n = n0 + j * 16 + cc;
      float bn = be[n];
#pragma unroll
      for (int r = 0; r < 4; ++r) {
        int m = m0 + i * 16 + rr + r;
        Cb[(size_t)m * 1024 + n] = f2b(acc[i][j][r] + bn);
      }
    }
}

// ---------------- skinny MFMA GEMM, tiled W: part[s][64][N] ----------------
__global__ __launch_bounds__(256) void k_skinny_t(const short* __restrict__ A, int lda,
                                                  const short* __restrict__ Wt, int ldw,
                                                  int N, int kchunk, float* __restrict__ part) {
  int wave = threadIdx.x >> 6, lane = threadIdx.x & 63;
  int n0 = blockIdx.x * 128 + wave * 32;
  int kb = blockIdx.y * kchunk;
  int lr = lane & 15, lk = (lane >> 4) * 8;
  int ntk = ldw >> 5, ntN = N >> 4;
  int nt0 = n0 >> 4;
  bool ok0 = nt0 < ntN, ok1 = nt0 + 1 < ntN;
  f32x4 acc[4][2] = {};
  const short* Ab = A + (size_t)lr * lda + kb + lk;
  const short* Wb0 = Wt + (((size_t)(ok0 ? nt0 : 0) * ntk + (kb >> 5)) << 9) + lane * 8;
  const short* Wb1 = Wt + (((size_t)(ok1 ? nt0 + 1 : 0) * ntk + (kb >> 5)) << 9) + lane * 8;
  const bf16x8 zv = {0, 0, 0, 0, 0, 0, 0, 0};
  int nkt = kchunk >> 5;
  for (int kt = 0; kt < nkt; ++kt) {
    bf16x8 a[4], b0, b1;
#pragma unroll
    for (int i = 0; i < 4; ++i) a[i] = *(const bf16x8*)(Ab + (size_t)i * 16 * lda + kt * 32);
    b0 = ok0 ? *(const bf16x8*)(Wb0 + ((size_t)kt << 9)) : zv;
    b1 = ok1 ? *(const bf16x8*)(Wb1 + ((size_t)kt << 9)) : zv;
#pragma unroll
    for (int i = 0; i < 4; ++i) {
      acc[i][0] = __builtin_amdgcn_mfma_f32_16x16x32_bf16(a[i], b0, acc[i][0], 0, 0, 0);
      acc[i][1] = __builtin_amdgcn_mfma_f32_16x16x32_bf16(a[i], b1, acc[i][1], 0, 0, 0);
    }
  }
  float* po = part + (size_t)blockIdx.y * 64 * N;
  int rr = (lane >> 4) * 4, cc = lane & 15;
#pragma unroll
  for (int i = 0; i < 4; ++i)
#pragma unroll
    for (int j = 0; j < 2; ++j) {
      int n = n0 + j * 16 + cc;
      if (n < N) {
#pragma unroll
        for (int r = 0; r < 4; ++r) {
          int m = i * 16 + rr + r;
          po[(size_t)m * N + n] = acc[i][j][r];
        }
      }
    }
}

// ---------------- LSTM gates: sum nsplit partials + biases, update c, forward h ----------------
__global__ void k_gates(const float* __restrict__ part, int nsplit,
                        const float* __restrict__ bih, const float* __restrict__ bhh,
                        float* __restrict__ c,
                        const short* __restrict__ hold, int ldo,
                        short* __restrict__ dst1, int ld1,
                        short* __restrict__ dst2, int ld2,
                        const int* __restrict__ declen, int t) {
  int idx = blockIdx.x * 256 + threadIdx.x;  // 65536
  int b = idx >> 10, j = idx & 1023;
  const float* pb = part + (size_t)b * 4096;
  float gi = bih[j] + bhh[j];
  float gf = bih[1024 + j] + bhh[1024 + j];
  float gg = bih[2048 + j] + bhh[2048 + j];
  float go = bih[3072 + j] + bhh[3072 + j];
  for (int s = 0; s < nsplit; ++s) {
    const float* p = pb + (size_t)s * 64 * 4096;
    gi += p[j]; gf += p[j + 1024]; gg += p[j + 2048]; go += p[j + 3072];
  }
  float si = 1.0f / (1.0f + expf(-gi));
  float sf = 1.0f / (1.0f + expf(-gf));
  float so = 1.0f / (1.0f + expf(-go));
  float cn = sf * c[idx] + si * tanhf(gg);
  float hn = so * tanhf(cn);
  short hb;
  if (t < declen[b]) {
    c[idx] = cn;
    hb = f2b(hn);
  } else {
    hb = hold[b * ldo + j];
  }
  dst1[b * ld1 + j] = hb;
  dst2[b * ld2 + j] = hb;
}

// ---------------- e[b,p] = Wf . relu(att1[b,p,:] + att2) + bf ----------------
__global__ __launch_bounds__(256) void k_e(const short* __restrict__ att1,
                                           const float* __restrict__ att2p,
                                           const float* __restrict__ bd,
                                           const float* __restrict__ Wf,
                                           const float* __restrict__ bf,
                                           float* __restrict__ e) {
  __shared__ float a2[1024];
  int b = blockIdx.x / 49, pq = blockIdx.x % 49;
  for (int i = threadIdx.x; i < 1024; i += 256) {
    float s = bd[i];
#pragma unroll
    for (int q = 0; q < 4; ++q) s += att2p[q * 65536 + b * 1024 + i];
    a2[i] = s;
  }
  __syncthreads();
  int wave = threadIdx.x >> 6, lane = threadIdx.x & 63;
  int p = pq * 4 + wave;
  const short* a1 = att1 + ((size_t)(b * P_ + p)) * 1024;
  float s = 0.0f;
#pragma unroll
  for (int h = 0; h < 2; ++h) {
    int k0 = lane * 8 + h * 512;
    bf16x8 v = *(const bf16x8*)(a1 + k0);
#pragma unroll
    for (int j = 0; j < 8; ++j) s += Wf[k0 + j] * fmaxf(b2f(v[j]) + a2[k0 + j], 0.0f);
  }
#pragma unroll
  for (int off = 32; off; off >>= 1) s += __shfl_down(s, off);
  if (lane == 0) e[b * P_ + p] = s + bf[0];
}

// ---------------- softmax (in-block) + awe ----------------
__global__ __launch_bounds__(256) void k_sawe(const float* __restrict__ e,
                                              const short* __restrict__ encb,
                                              short* __restrict__ xc2t) {
  int b = blockIdx.x, ch = blockIdx.y;  // ch < 8
  __shared__ float al[P_];
  __shared__ float red[8][256];
  int tid = threadIdx.x;
  if (tid < 64) {
    float vals[4];
    float mx = -1e30f;
#pragma unroll
    for (int q = 0; q < 4; ++q) {
      int p = tid + q * 64;
      vals[q] = (p < P_) ? e[b * P_ + p] : -1e30f;
      mx = fmaxf(mx, vals[q]);
    }
#pragma unroll
    for (int off = 32; off; off >>= 1) mx = fmaxf(mx, __shfl_xor(mx, off));
    float sum = 0.0f;
#pragma unroll
    for (int q = 0; q < 4; ++q) {
      int p = tid + q * 64;
      vals[q] = (p < P_) ? expf(vals[q] - mx) : 0.0f;
      sum += vals[q];
    }
#pragma unroll
    for (int off = 32; off; off >>= 1) sum += __shfl_xor(sum, off);
    float inv = 1.0f / sum;
#pragma unroll
    for (int q = 0; q < 4; ++q) {
      int p = tid + q * 64;
      if (p < P_) al[p] = vals[q] * inv;
    }
  }
  __syncthreads();
  int pg = tid >> 5, cg = tid & 31;
  int col = ch * 256 + cg * 8;
  const short* src = encb + (size_t)b * P_ * ENC_ + col;
  float acc[8] = {};
  for (int p = pg; p < P_; p += 8) {
    bf16x8 v = *(const bf16x8*)(src + (size_t)p * ENC_);
    float ap = al[p];
#pragma unroll
    for (int j = 0; j < 8; ++j) acc[j] += ap * b2f(v[j]);
  }
#pragma unroll
  for (int j = 0; j < 8; ++j) red[pg][cg * 8 + j] = acc[j];
  __syncthreads();
  float s = 0.0f;
#pragma unroll
  for (int g = 0; g < 8; ++g) s += red[g][tid];
  xc2t[b * 4096 + ch * 256 + tid] = f2b(s);
}

// ---------------- batched head GEMM over all t: out[(b*TDEC+t)*V + n] ----------------
__global__ __launch_bounds__(256) void k_head_bt(const short* __restrict__ Aall,
                                                 const short* __restrict__ Wt,
                                                 const float* __restrict__ bias,
                                                 float* __restrict__ outp,
                                                 const int* __restrict__ declen) {
  int t = blockIdx.y;
  const short* A = Aall + (size_t)t * (64 * 4096);
  int wave = threadIdx.x >> 6, lane = threadIdx.x & 63;
  int nt = blockIdx.x * 4 + wave;  // 157 blocks -> nt in [0,628)
  bool ok = nt < (V_ >> 4);        // 625 tiles
  int lr = lane & 15, lk = (lane >> 4) * 8;
  f32x4 acc[4] = {};
  const short* Ab = A + (size_t)lr * 4096 + lk;
  const short* Wb = Wt + ((size_t)(ok ? nt : 0) * 32 << 9) + lane * 8;
  const bf16x8 zv = {0, 0, 0, 0, 0, 0, 0, 0};
  for (int kt = 0; kt < 32; ++kt) {
    bf16x8 bfr = ok ? *(const bf16x8*)(Wb + ((size_t)kt << 9)) : zv;
#pragma unroll
    for (int i = 0; i < 4; ++i) {
      bf16x8 afr = *(const bf16x8*)(Ab + (size_t)i * 16 * 4096 + kt * 32);
      acc[i] = __builtin_amdgcn_mfma_f32_16x16x32_bf16(afr, bfr, acc[i], 0, 0, 0);
    }
  }
  int rr = (lane >> 4) * 4, cc = lane & 15;
  int n = nt * 16 + cc;
  if (n < V_) {
    float bn = bias[n];
#pragma unroll
    for (int i = 0; i < 4; ++i) {
#pragma unroll
      for (int r = 0; r < 4; ++r) {
        int b = i * 16 + rr + r;
        float val = acc[i][r] + bn;
        outp[((size_t)b * TDEC_ + t) * V_ + n] = (t < declen[b]) ? val : 0.0f;
      }
    }
  }
}

// ---------------- host ----------------
extern "C" void kernel_launch(void* const* d_in, const int* in_sizes, int n_in,
                              void* d_out, int out_size, void* d_ws, size_t ws_size,
                              hipStream_t stream) {
  (void)in_sizes; (void)n_in; (void)d_ws; (void)ws_size; (void)out_size;
  const float* enc  = (const float*)d_in[0];
  const int*   caps = (const int*)d_in[1];
  const int*   cl   = (const int*)d_in[2];
  const float* emb  = (const float*)d_in[3];
  const float* We   = (const float*)d_in[4];
  const float* be   = (const float*)d_in[5];
  const float* Wd   = (const float*)d_in[6];
  const float* bd   = (const float*)d_in[7];
  const float* Wf   = (const float*)d_in[8];
  const float* bf   = (const float*)d_in[9];
  const float* Wih1 = (const float*)d_in[10];
  const float* Whh1 = (const float*)d_in[11];
  const float* bih1 = (const float*)d_in[12];
  const float* bhh1 = (const float*)d_in[13];
  const float* Wih2 = (const float*)d_in[14];
  const float* Whh2 = (const float*)d_in[15];
  const float* bih2 = (const float*)d_in[16];
  const float* bhh2 = (const float*)d_in[17];
  const float* Wfc1 = (const float*)d_in[18];
  const float* bfc1 = (const float*)d_in[19];
  const float* Wfc  = (const float*)d_in[20];
  const float* bfc  = (const float*)d_in[21];
  float* out = (float*)d_out;

  short *encb, *encbt, *att1, *Wc1t, *Wc2t, *Webt, *Wdt, *Wfc1t, *Wfct, *xc1, *xc2, *em;
  float *part, *att2p, *e, *c1, *c2;
  int* ib;
  hipGetSymbolAddress((void**)&encb, HIP_SYMBOL(g_encb));
  hipGetSymbolAddress((void**)&encbt, HIP_SYMBOL(g_encbt));
  hipGetSymbolAddress((void**)&att1, HIP_SYMBOL(g_att1));
  hipGetSymbolAddress((void**)&Wc1t, HIP_SYMBOL(g_Wc1t));
  hipGetSymbolAddress((void**)&Wc2t, HIP_SYMBOL(g_Wc2t));
  hipGetSymbolAddress((void**)&Webt, HIP_SYMBOL(g_Webt));
  hipGetSymbolAddress((void**)&Wdt, HIP_SYMBOL(g_Wdt));
  hipGetSymbolAddress((void**)&Wfc1t, HIP_SYMBOL(g_Wfc1t));
  hipGetSymbolAddress((void**)&Wfct, HIP_SYMBOL(g_Wfct));
  hipGetSymbolAddress((void**)&xc1, HIP_SYMBOL(g_xc1));
  hipGetSymbolAddress((void**)&xc2, HIP_SYMBOL(g_xc2));
  hipGetSymbolAddress((void**)&em, HIP_SYMBOL(g_em));
  hipGetSymbolAddress((void**)&part, HIP_SYMBOL(g_part));
  hipGetSymbolAddress((void**)&att2p, HIP_SYMBOL(g_att2p));
  hipGetSymbolAddress((void**)&e, HIP_SYMBOL(g_e));
  hipGetSymbolAddress((void**)&c1, HIP_SYMBOL(g_c1));
  hipGetSymbolAddress((void**)&c2, HIP_SYMBOL(g_c2));
  hipGetSymbolAddress((void**)&ib, HIP_SYMBOL(g_ibuf));
  int* sind = ib;
  int* declen = ib + 64;
  int* caps_s = ib + 128;

  float* out_preds  = out;
  float* out_preds1 = out + (size_t)B_ * TDEC_ * V_;
  float* out_caps   = out + 2ull * B_ * TDEC_ * V_;
  float* out_declen = out_caps + B_ * MAXLEN_;
  float* out_sind   = out_declen + B_;

  // ---- preprocessing ----
  k_sort<<<1, 64, 0, stream>>>(cl, caps, sind, declen, caps_s, out_caps, out_declen, out_sind);
  hipMemsetAsync(c1, 0, 64 * 1024 * sizeof(float), stream);
  hipMemsetAsync(c2, 0, 64 * 1024 * sizeof(float), stream);
  hipMemsetAsync(xc1, 0, (size_t)64 * 5120 * sizeof(short), stream);  // t=0 buffer
  hipMemsetAsync(xc2, 0, (size_t)64 * 4096 * sizeof(short), stream);  // t=0 buffer
  k_encprep<<<12544, 256, 0, stream>>>(enc, sind, encb, encbt);
  k_encmeanb<<<64, 256, 0, stream>>>(encb, em);
  k_prefill<<<dim3(19, 64), 256, 0, stream>>>(emb, caps_s, em, xc1);
  k_f2bt<<<8192, 256, 0, stream>>>(Wih1, 4096, Wc1t, 5120, 0);
  k_f2bt<<<2048, 256, 0, stream>>>(Whh1, 1024, Wc1t, 5120, 4096);
  k_f2bt<<<6144, 256, 0, stream>>>(Wih2, 3072, Wc2t, 4096, 0);
  k_f2bt<<<2048, 256, 0, stream>>>(Whh2, 1024, Wc2t, 4096, 3072);
  k_f2bt<<<1024, 256, 0, stream>>>(We, 2048, Webt, 2048, 0);
  k_f2bt<<<512, 256, 0, stream>>>(Wd, 1024, Wdt, 1024, 0);
  k_f2bt<<<5000, 256, 0, stream>>>(Wfc1, 1024, Wfc1t, 1024, 0);
  k_f2bt<<<5000, 256, 0, stream>>>(Wfc, 1024, Wfct, 1024, 0);
  k_att1_t<<<dim3(98, 2), 1024, 0, stream>>>(encbt, Webt, be, att1);

  // ---- decode loop ----
  for (int t = 0; t < TDEC_; ++t) {
    short* x1t = xc1 + (size_t)t * 64 * 5120;
    short* x1n = xc1 + (size_t)(t + 1) * 64 * 5120;
    short* x2t = xc2 + (size_t)t * 64 * 4096;
    short* x2n = xc2 + (size_t)(t + 1) * 64 * 4096;
    // LSTM1: xc1_t @ Wcat1^T  (K=5120, KS=8 -> 640)
    k_skinny_t<<<dim3(32, 8), 256, 0, stream>>>(x1t, 5120, Wc1t, 5120, 4096, 640, part);
    k_gates<<<256, 256, 0, stream>>>(part, 8, bih1, bhh1, c1, x1t + 4096, 5120,
                                     x1n + 4096, 5120, x2t + 2048, 4096, declen, t);
    // att2 = h1 @ Wd^T  (K=1024, KS=4 -> 256)
    k_skinny_t<<<dim3(8, 4), 256, 0, stream>>>(x2t + 2048, 4096, Wdt, 1024, 1024, 256, att2p);
    k_e<<<3136, 256, 0, stream>>>(att1, att2p, bd, Wf, bf, e);
    k_sawe<<<dim3(64, 8), 256, 0, stream>>>(e, encb, x2t);
    // LSTM2: xc2_t @ Wcat2^T  (K=4096, KS=8 -> 512)
    k_skinny_t<<<dim3(32, 8), 256, 0, stream>>>(x2t, 4096, Wc2t, 4096, 4096, 512, part);
    k_gates<<<256, 256, 0, stream>>>(part, 8, bih2, bhh2, c2, x1t, 5120,
                                     x1n, 5120, x2n + 3072, 4096, declen, t);
  }
  // ---- batched output heads over all t ----
  k_head_bt<<<dim3(157, 19), 256, 0, stream>>>(xc2 + 2048, Wfc1t, bfc1, out_preds1, declen);
  k_head_bt<<<dim3(157, 19), 256, 0, stream>>>(xc2 + 64 * 4096 + 3072, Wfct, bfc, out_preds, declen);
}

// Round 7
// 1944.357 us; speedup vs baseline: 2.0947x; 1.1099x over previous
//
#include <hip/hip_runtime.h>
#include <cmath>

#define B_ 64
#define P_ 196
#define ENC_ 2048
#define DEC_ 1024
#define V_ 10000
#define MAXLEN_ 20
#define TDEC_ 19

typedef __attribute__((ext_vector_type(8))) short bf16x8;
typedef __attribute__((ext_vector_type(4))) float f32x4;

// Tiled weight layout: tile = 16 rows x 32 k = 512 bf16 = 1KB, k-tiles fastest.
// element (r,k): offset = ((r>>4)*(K>>5) + (k>>5))*512 + ((r&15) | (((k>>3)&3)<<4))*8 + (k&7)

// ---------------- static device buffers ----------------
__device__ __align__(16) short g_encb[(size_t)12544 * 2048];    // sorted enc, bf16 row-major
__device__ __align__(16) short g_encbt[(size_t)12544 * 2048];   // sorted enc, bf16 TILED
__device__ __align__(16) short g_att1[(size_t)12544 * 1024];    // att1, bf16 (incl. be)
__device__ __align__(16) short g_Wp1t[(size_t)4096 * 2048];     // [Wih1[:, :1024] | Whh1] tiled
__device__ __align__(16) short g_Wmid1t[(size_t)4096 * 3072];   // Wih1[:, 1024:4096] tiled
__device__ __align__(16) short g_Wc2t[(size_t)4096 * 4096];     // [Wih2(3072)|Whh2(1024)] tiled
__device__ __align__(16) short g_Webt[(size_t)1024 * 2048];     // We tiled
__device__ __align__(16) short g_Wdt[(size_t)1024 * 1024];      // Wd tiled
__device__ __align__(16) short g_Wfc1t[(size_t)10000 * 1024];   // Wfc1 tiled
__device__ __align__(16) short g_Wfct[(size_t)10000 * 1024];    // Wfc tiled
__device__ __align__(16) short g_xs1[(size_t)20 * 64 * 2048];   // per-t [h2|h1] (LSTM1 step A)
__device__ __align__(16) short g_xmid[(size_t)19 * 64 * 3072];  // per-t [em|emb_t]
__device__ __align__(16) short g_xc2[(size_t)20 * 64 * 4096];   // per-t [awe|h1|h2]
__device__ __align__(16) short g_em[64 * 2048];                 // enc mean, bf16
__device__ __align__(16) float g_pre1[(size_t)19 * 64 * 4096];  // precomputed mid-gates
__device__ __align__(16) float g_part[(size_t)8 * 64 * 4096];
__device__ __align__(16) float g_att2p[(size_t)4 * 64 * 1024];
__device__ __align__(16) float g_e[64 * P_];
__device__ __align__(16) float g_c1[64 * 1024];
__device__ __align__(16) float g_c2[64 * 1024];
__device__ int g_ibuf[64 + 64 + 64 * MAXLEN_];

__device__ __forceinline__ short f2b(float f) {
  unsigned u = __float_as_uint(f);
  u += 0x7FFFu + ((u >> 16) & 1u);
  return (short)(u >> 16);
}
__device__ __forceinline__ float b2f(short s) {
  return __uint_as_float(((unsigned)(unsigned short)s) << 16);
}

// ---------------- sort + int-ish outputs ----------------
__global__ void k_sort(const int* __restrict__ cl_in, const int* __restrict__ caps_in,
                       int* __restrict__ sind, int* __restrict__ declen, int* __restrict__ caps_s,
                       float* __restrict__ out_caps, float* __restrict__ out_declen,
                       float* __restrict__ out_sind) {
  int i = threadIdx.x;  // 64 threads
  __shared__ int cl[B_];
  cl[i] = cl_in[i];
  __syncthreads();
  int my = cl[i], pos = 0;
  for (int j = 0; j < B_; ++j) {
    int cj = cl[j];
    if (cj > my || (cj == my && j < i)) pos++;
  }
  sind[pos] = i;
  __syncthreads();
  int sb = sind[i];
  int dl = cl[sb] - 1;
  declen[i] = dl;
  out_declen[i] = (float)dl;
  out_sind[i] = (float)sb;
  for (int t = 0; t < MAXLEN_; ++t) {
    int v = caps_in[sb * MAXLEN_ + t];
    caps_s[i * MAXLEN_ + t] = v;
    out_caps[i * MAXLEN_ + t] = (float)v;
  }
}

// gather-sort + fp32->bf16 encoder: row-major AND tiled copies
__global__ __launch_bounds__(256) void k_encprep(const float* __restrict__ enc,
                                                 const int* __restrict__ sind,
                                                 short* __restrict__ encb,
                                                 short* __restrict__ encbt) {
  int mg = blockIdx.x;  // 12544
  int b = mg / P_, p = mg - b * P_;
  int tid = threadIdx.x;
  const float* src = enc + ((size_t)sind[b] * P_ + p) * ENC_ + tid * 8;
  float4 a = *(const float4*)src;
  float4 c = *(const float4*)(src + 4);
  bf16x8 v;
  v[0] = f2b(a.x); v[1] = f2b(a.y); v[2] = f2b(a.z); v[3] = f2b(a.w);
  v[4] = f2b(c.x); v[5] = f2b(c.y); v[6] = f2b(c.z); v[7] = f2b(c.w);
  *(bf16x8*)(encb + (size_t)mg * ENC_ + tid * 8) = v;
  size_t off = (((size_t)(mg >> 4) * 64 + (tid >> 2)) << 9) +
               (((mg & 15) | ((tid & 3) << 4)) << 3);
  *(bf16x8*)(encbt + off) = v;
}

// enc mean -> g_em (bf16)
__global__ __launch_bounds__(256) void k_encmeanb(const short* __restrict__ encb,
                                                  short* __restrict__ em) {
  int b = blockIdx.x;
  int col0 = threadIdx.x * 8;
  const short* src = encb + (size_t)b * P_ * ENC_ + col0;
  float acc[8] = {};
  for (int p = 0; p < P_; ++p) {
    bf16x8 v = *(const bf16x8*)(src + (size_t)p * ENC_);
#pragma unroll
    for (int j = 0; j < 8; ++j) acc[j] += b2f(v[j]);
  }
#pragma unroll
  for (int j = 0; j < 8; ++j) em[b * 2048 + col0 + j] = f2b(acc[j] * (1.0f / 196.0f));
}

// prefill xmid[t][b] = [em(2048) | emb_t(1024)]
__global__ __launch_bounds__(256) void k_prefill(const float* __restrict__ emb,
                                                 const int* __restrict__ caps_s,
                                                 const short* __restrict__ em,
                                                 short* __restrict__ xmid) {
  int t = blockIdx.x, b = blockIdx.y, tid = threadIdx.x;  // (19, 64)
  short* xr = xmid + ((size_t)t * 64 + b) * 3072;
  int i = tid * 8;
  *(bf16x8*)(xr + i) = *(const bf16x8*)(em + b * 2048 + i);
  int cap = caps_s[b * MAXLEN_ + t];
  int j = tid * 4;
  float4 v = *(const float4*)(emb + (size_t)cap * 1024 + j);
  short4 o;
  o.x = f2b(v.x); o.y = f2b(v.y); o.z = f2b(v.z); o.w = f2b(v.w);
  *(short4*)(xr + 2048 + j) = o;
}

// fp32 row-major src[r][Kstride], col-slice [c0, c0+ncols) -> bf16 TILED dst (Ktot, koff)
__global__ void k_f2bts(const float* __restrict__ src, int Kstride, int c0, int ncols,
                        short* __restrict__ dst, int Ktot, int koff) {
  int idx = blockIdx.x * 256 + threadIdx.x;
  int kc = ncols >> 3;
  int r = idx / kc, k8 = (idx - r * kc) << 3;
  const float* s = src + (size_t)r * Kstride + c0 + k8;
  float4 a = *(const float4*)s;
  float4 c = *(const float4*)(s + 4);
  bf16x8 v;
  v[0] = f2b(a.x); v[1] = f2b(a.y); v[2] = f2b(a.z); v[3] = f2b(a.w);
  v[4] = f2b(c.x); v[5] = f2b(c.y); v[6] = f2b(c.z); v[7] = f2b(c.w);
  int kg = koff + k8;
  size_t off = (((size_t)(r >> 4) * (Ktot >> 5) + (kg >> 5)) << 9) +
               (((r & 15) | (((kg >> 3) & 3) << 4)) << 3);
  *(bf16x8*)(dst + off) = v;
}

// ---------------- att1 = enc @ We^T + be -> bf16 (12544x1024), both TILED ----------------
__global__ __launch_bounds__(1024) void k_att1_t(const short* __restrict__ At,
                                                 const short* __restrict__ Wt,
                                                 const float* __restrict__ be,
                                                 short* __restrict__ Cb) {
  int wave = threadIdx.x >> 6, lane = threadIdx.x & 63;
  int mt0 = blockIdx.x * 8 + (wave >> 3) * 4;
  int nt0 = blockIdx.y * 32 + (wave & 7) * 4;
  f32x4 acc[4][4] = {};
  const short* Ab = At + ((size_t)mt0 * 64 << 9) + lane * 8;  // 64 k-tiles
  const short* Wb = Wt + ((size_t)nt0 * 64 << 9) + lane * 8;
  for (int kt = 0; kt < 64; ++kt) {
    bf16x8 a[4], b[4];
#pragma unroll
    for (int i = 0; i < 4; ++i) a[i] = *(const bf16x8*)(Ab + (((size_t)i * 64 + kt) << 9));
#pragma unroll
    for (int j = 0; j < 4; ++j) b[j] = *(const bf16x8*)(Wb + (((size_t)j * 64 + kt) << 9));
#pragma unroll
    for (int i = 0; i < 4; ++i)
#pragma unroll
      for (int j = 0; j < 4; ++j)
        acc[i][j] = __builtin_amdgcn_mfma_f32_16x16x32_bf16(a[i], b[j], acc[i][j], 0, 0, 0);
  }
  int rr = (lane >> 4) * 4, cc = lane & 15;
  int m0 = mt0 * 16, n0 = nt0 * 16;
#pragma unroll
  for (int i = 0; i < 4; ++i)
#pragma unroll
    for (int j = 0; j < 4; ++j) {
      int n = n0 + j * 16 + cc;
      float bn = be[n];
#pragma unroll
      for (int r = 0; r < 4; ++r) {
        int m = m0 + i * 16 + rr + r;
        Cb[(size_t)m * 1024 + n] = f2b(acc[i][j][r] + bn);
      }
    }
}

// ---------------- skinny MFMA GEMM, tiled W: part[s][64][N] ----------------
__global__ __launch_bounds__(256) void k_skinny_t(const short* __restrict__ A, int lda,
                                                  const short* __restrict__ Wt, int ldw,
                                                  int N, int kchunk, float* __restrict__ part) {
  int wave = threadIdx.x >> 6, lane = threadIdx.x & 63;
  int n0 = blockIdx.x * 128 + wave * 32;
  int kb = blockIdx.y * kchunk;
  int lr = lane & 15, lk = (lane >> 4) * 8;
  int ntk = ldw >> 5;
  int nt0 = n0 >> 4;
  f32x4 acc[4][2] = {};
  const short* Ab = A + (size_t)lr * lda + kb + lk;
  const short* Wb0 = Wt + (((size_t)nt0 * ntk + (kb >> 5)) << 9) + lane * 8;
  const short* Wb1 = Wt + (((size_t)(nt0 + 1) * ntk + (kb >> 5)) << 9) + lane * 8;
  int nkt = kchunk >> 5;
  for (int kt = 0; kt < nkt; ++kt) {
    bf16x8 a[4], b0, b1;
#pragma unroll
    for (int i = 0; i < 4; ++i) a[i] = *(const bf16x8*)(Ab + (size_t)i * 16 * lda + kt * 32);
    b0 = *(const bf16x8*)(Wb0 + ((size_t)kt << 9));
    b1 = *(const bf16x8*)(Wb1 + ((size_t)kt << 9));
#pragma unroll
    for (int i = 0; i < 4; ++i) {
      acc[i][0] = __builtin_amdgcn_mfma_f32_16x16x32_bf16(a[i], b0, acc[i][0], 0, 0, 0);
      acc[i][1] = __builtin_amdgcn_mfma_f32_16x16x32_bf16(a[i], b1, acc[i][1], 0, 0, 0);
    }
  }
  float* po = part + (size_t)blockIdx.y * 64 * N;
  int rr = (lane >> 4) * 4, cc = lane & 15;
#pragma unroll
  for (int i = 0; i < 4; ++i)
#pragma unroll
    for (int j = 0; j < 2; ++j) {
      int n = n0 + j * 16 + cc;
#pragma unroll
      for (int r = 0; r < 4; ++r) {
        int m = i * 16 + rr + r;
        po[(size_t)m * N + n] = acc[i][j][r];
      }
    }
}

// ---------------- batched mid GEMM: pre1[t][64][4096] = xmid[t] @ Wmid^T (K=3072) ----------------
__global__ __launch_bounds__(256) void k_mid_bt(const short* __restrict__ xmid,
                                                const short* __restrict__ Wt,
                                                float* __restrict__ pre1) {
  int t = blockIdx.y;
  const short* A = xmid + (size_t)t * 64 * 3072;
  int wave = threadIdx.x >> 6, lane = threadIdx.x & 63;
  int n0 = blockIdx.x * 128 + wave * 32;  // 32 blocks x
  int lr = lane & 15, lk = (lane >> 4) * 8;
  int nt0 = n0 >> 4;
  f32x4 acc[4][2] = {};
  const short* Ab = A + (size_t)lr * 3072 + lk;
  const short* Wb0 = Wt + (((size_t)nt0 * 96) << 9) + lane * 8;      // ntk = 96
  const short* Wb1 = Wt + (((size_t)(nt0 + 1) * 96) << 9) + lane * 8;
  for (int kt = 0; kt < 96; ++kt) {
    bf16x8 a[4], b0, b1;
#pragma unroll
    for (int i = 0; i < 4; ++i) a[i] = *(const bf16x8*)(Ab + (size_t)i * 16 * 3072 + kt * 32);
    b0 = *(const bf16x8*)(Wb0 + ((size_t)kt << 9));
    b1 = *(const bf16x8*)(Wb1 + ((size_t)kt << 9));
#pragma unroll
    for (int i = 0; i < 4; ++i) {
      acc[i][0] = __builtin_amdgcn_mfma_f32_16x16x32_bf16(a[i], b0, acc[i][0], 0, 0, 0);
      acc[i][1] = __builtin_amdgcn_mfma_f32_16x16x32_bf16(a[i], b1, acc[i][1], 0, 0, 0);
    }
  }
  float* po = pre1 + (size_t)t * 64 * 4096;
  int rr = (lane >> 4) * 4, cc = lane & 15;
#pragma unroll
  for (int i = 0; i < 4; ++i)
#pragma unroll
    for (int j = 0; j < 2; ++j) {
      int n = n0 + j * 16 + cc;
#pragma unroll
      for (int r = 0; r < 4; ++r) {
        int m = i * 16 + rr + r;
        po[(size_t)m * 4096 + n] = acc[i][j][r];
      }
    }
}

// ---------------- LSTM gates: biases + nsplit partials (+ pre), update c, forward h ----------------
__global__ void k_gates(const float* __restrict__ part, int nsplit,
                        const float* __restrict__ pre,
                        const float* __restrict__ bih, const float* __restrict__ bhh,
                        float* __restrict__ c,
                        const short* __restrict__ hold, int ldo,
                        short* __restrict__ dst1, int ld1,
                        short* __restrict__ dst2, int ld2,
                        const int* __restrict__ declen, int t) {
  int idx = blockIdx.x * 256 + threadIdx.x;  // 65536
  int b = idx >> 10, j = idx & 1023;
  const float* pb = part + (size_t)b * 4096;
  float gi = bih[j] + bhh[j];
  float gf = bih[1024 + j] + bhh[1024 + j];
  float gg = bih[2048 + j] + bhh[2048 + j];
  float go = bih[3072 + j] + bhh[3072 + j];
  if (pre) {
    const float* pp = pre + (size_t)b * 4096;
    gi += pp[j]; gf += pp[j + 1024]; gg += pp[j + 2048]; go += pp[j + 3072];
  }
  for (int s = 0; s < nsplit; ++s) {
    const float* p = pb + (size_t)s * 64 * 4096;
    gi += p[j]; gf += p[j + 1024]; gg += p[j + 2048]; go += p[j + 3072];
  }
  float si = 1.0f / (1.0f + expf(-gi));
  float sf = 1.0f / (1.0f + expf(-gf));
  float so = 1.0f / (1.0f + expf(-go));
  float cn = sf * c[idx] + si * tanhf(gg);
  float hn = so * tanhf(cn);
  short hb;
  if (t < declen[b]) {
    c[idx] = cn;
    hb = f2b(hn);
  } else {
    hb = hold[b * ldo + j];
  }
  dst1[b * ld1 + j] = hb;
  dst2[b * ld2 + j] = hb;
}

// ---------------- e[b,p] = Wf . relu(att1[b,p,:] + att2) + bf ----------------
__global__ __launch_bounds__(256) void k_e(const short* __restrict__ att1,
                                           const float* __restrict__ att2p,
                                           const float* __restrict__ bd,
                                           const float* __restrict__ Wf,
                                           const float* __restrict__ bf,
                                           float* __restrict__ e) {
  __shared__ float a2[1024];
  int b = blockIdx.x / 49, pq = blockIdx.x % 49;
  for (int i = threadIdx.x; i < 1024; i += 256) {
    float s = bd[i];
#pragma unroll
    for (int q = 0; q < 4; ++q) s += att2p[q * 65536 + b * 1024 + i];
    a2[i] = s;
  }
  __syncthreads();
  int wave = threadIdx.x >> 6, lane = threadIdx.x & 63;
  int p = pq * 4 + wave;
  const short* a1 = att1 + ((size_t)(b * P_ + p)) * 1024;
  float s = 0.0f;
#pragma unroll
  for (int h = 0; h < 2; ++h) {
    int k0 = lane * 8 + h * 512;
    bf16x8 v = *(const bf16x8*)(a1 + k0);
#pragma unroll
    for (int j = 0; j < 8; ++j) s += Wf[k0 + j] * fmaxf(b2f(v[j]) + a2[k0 + j], 0.0f);
  }
#pragma unroll
  for (int off = 32; off; off >>= 1) s += __shfl_down(s, off);
  if (lane == 0) e[b * P_ + p] = s + bf[0];
}

// ---------------- softmax (in-block) + awe ----------------
__global__ __launch_bounds__(256) void k_sawe(const float* __restrict__ e,
                                              const short* __restrict__ encb,
                                              short* __restrict__ xc2t) {
  int b = blockIdx.x, ch = blockIdx.y;  // ch < 8
  __shared__ float al[P_];
  __shared__ float red[8][256];
  int tid = threadIdx.x;
  if (tid < 64) {
    float vals[4];
    float mx = -1e30f;
#pragma unroll
    for (int q = 0; q < 4; ++q) {
      int p = tid + q * 64;
      vals[q] = (p < P_) ? e[b * P_ + p] : -1e30f;
      mx = fmaxf(mx, vals[q]);
    }
#pragma unroll
    for (int off = 32; off; off >>= 1) mx = fmaxf(mx, __shfl_xor(mx, off));
    float sum = 0.0f;
#pragma unroll
    for (int q = 0; q < 4; ++q) {
      int p = tid + q * 64;
      vals[q] = (p < P_) ? expf(vals[q] - mx) : 0.0f;
      sum += vals[q];
    }
#pragma unroll
    for (int off = 32; off; off >>= 1) sum += __shfl_xor(sum, off);
    float inv = 1.0f / sum;
#pragma unroll
    for (int q = 0; q < 4; ++q) {
      int p = tid + q * 64;
      if (p < P_) al[p] = vals[q] * inv;
    }
  }
  __syncthreads();
  int pg = tid >> 5, cg = tid & 31;
  int col = ch * 256 + cg * 8;
  const short* src = encb + (size_t)b * P_ * ENC_ + col;
  float acc[8] = {};
  for (int p = pg; p < P_; p += 8) {
    bf16x8 v = *(const bf16x8*)(src + (size_t)p * ENC_);
    float ap = al[p];
#pragma unroll
    for (int j = 0; j < 8; ++j) acc[j] += ap * b2f(v[j]);
  }
#pragma unroll
  for (int j = 0; j < 8; ++j) red[pg][cg * 8 + j] = acc[j];
  __syncthreads();
  float s = 0.0f;
#pragma unroll
  for (int g = 0; g < 8; ++g) s += red[g][tid];
  xc2t[b * 4096 + ch * 256 + tid] = f2b(s);
}

// ---------------- batched head GEMM: 4 nt per wave, grid (40, 19) ----------------
__global__ __launch_bounds__(256) void k_head4(const short* __restrict__ Aall,
                                               const short* __restrict__ Wt,
                                               const float* __restrict__ bias,
                                               float* __restrict__ outp,
                                               const int* __restrict__ declen) {
  int t = blockIdx.y;
  const short* A = Aall + (size_t)t * (64 * 4096);
  int wave = threadIdx.x >> 6, lane = threadIdx.x & 63;
  int nt0 = blockIdx.x * 16 + wave * 4;  // 4 n-tiles per wave; 625 total
  int lr = lane & 15, lk = (lane >> 4) * 8;
  f32x4 acc[4][4] = {};
  const short* Ab = A + (size_t)lr * 4096 + lk;
  const short* Wb[4];
  bool ok[4];
#pragma unroll
  for (int j = 0; j < 4; ++j) {
    ok[j] = (nt0 + j) < (V_ >> 4);
    Wb[j] = Wt + ((size_t)(ok[j] ? nt0 + j : 0) * 32 << 9) + lane * 8;
  }
  for (int kt = 0; kt < 32; ++kt) {
    bf16x8 a[4], b[4];
#pragma unroll
    for (int j = 0; j < 4; ++j) b[j] = *(const bf16x8*)(Wb[j] + ((size_t)kt << 9));
#pragma unroll
    for (int i = 0; i < 4; ++i) a[i] = *(const bf16x8*)(Ab + (size_t)i * 16 * 4096 + kt * 32);
#pragma unroll
    for (int i = 0; i < 4; ++i)
#pragma unroll
      for (int j = 0; j < 4; ++j)
        acc[i][j] = __builtin_amdgcn_mfma_f32_16x16x32_bf16(a[i], b[j], acc[i][j], 0, 0, 0);
  }
  int rr = (lane >> 4) * 4, cc = lane & 15;
#pragma unroll
  for (int j = 0; j < 4; ++j) {
    if (!ok[j]) continue;
    int n = (nt0 + j) * 16 + cc;
    float bn = bias[n];
#pragma unroll
    for (int i = 0; i < 4; ++i) {
#pragma unroll
      for (int r = 0; r < 4; ++r) {
        int b = i * 16 + rr + r;
        float val = acc[i][j][r] + bn;
        outp[((size_t)b * TDEC_ + t) * V_ + n] = (t < declen[b]) ? val : 0.0f;
      }
    }
  }
}

// ---------------- host ----------------
extern "C" void kernel_launch(void* const* d_in, const int* in_sizes, int n_in,
                              void* d_out, int out_size, void* d_ws, size_t ws_size,
                              hipStream_t stream) {
  (void)in_sizes; (void)n_in; (void)d_ws; (void)ws_size; (void)out_size;
  const float* enc  = (const float*)d_in[0];
  const int*   caps = (const int*)d_in[1];
  const int*   cl   = (const int*)d_in[2];
  const float* emb  = (const float*)d_in[3];
  const float* We   = (const float*)d_in[4];
  const float* be   = (const float*)d_in[5];
  const float* Wd   = (const float*)d_in[6];
  const float* bd   = (const float*)d_in[7];
  const float* Wf   = (const float*)d_in[8];
  const float* bf   = (const float*)d_in[9];
  const float* Wih1 = (const float*)d_in[10];
  const float* Whh1 = (const float*)d_in[11];
  const float* bih1 = (const float*)d_in[12];
  const float* bhh1 = (const float*)d_in[13];
  const float* Wih2 = (const float*)d_in[14];
  const float* Whh2 = (const float*)d_in[15];
  const float* bih2 = (const float*)d_in[16];
  const float* bhh2 = (const float*)d_in[17];
  const float* Wfc1 = (const float*)d_in[18];
  const float* bfc1 = (const float*)d_in[19];
  const float* Wfc  = (const float*)d_in[20];
  const float* bfc  = (const float*)d_in[21];
  float* out = (float*)d_out;

  short *encb, *encbt, *att1, *Wp1t, *Wmid1t, *Wc2t, *Webt, *Wdt, *Wfc1t, *Wfct;
  short *xs1, *xmid, *xc2, *em;
  float *pre1, *part, *att2p, *e, *c1, *c2;
  int* ib;
  hipGetSymbolAddress((void**)&encb, HIP_SYMBOL(g_encb));
  hipGetSymbolAddress((void**)&encbt, HIP_SYMBOL(g_encbt));
  hipGetSymbolAddress((void**)&att1, HIP_SYMBOL(g_att1));
  hipGetSymbolAddress((void**)&Wp1t, HIP_SYMBOL(g_Wp1t));
  hipGetSymbolAddress((void**)&Wmid1t, HIP_SYMBOL(g_Wmid1t));
  hipGetSymbolAddress((void**)&Wc2t, HIP_SYMBOL(g_Wc2t));
  hipGetSymbolAddress((void**)&Webt, HIP_SYMBOL(g_Webt));
  hipGetSymbolAddress((void**)&Wdt, HIP_SYMBOL(g_Wdt));
  hipGetSymbolAddress((void**)&Wfc1t, HIP_SYMBOL(g_Wfc1t));
  hipGetSymbolAddress((void**)&Wfct, HIP_SYMBOL(g_Wfct));
  hipGetSymbolAddress((void**)&xs1, HIP_SYMBOL(g_xs1));
  hipGetSymbolAddress((void**)&xmid, HIP_SYMBOL(g_xmid));
  hipGetSymbolAddress((void**)&xc2, HIP_SYMBOL(g_xc2));
  hipGetSymbolAddress((void**)&em, HIP_SYMBOL(g_em));
  hipGetSymbolAddress((void**)&pre1, HIP_SYMBOL(g_pre1));
  hipGetSymbolAddress((void**)&part, HIP_SYMBOL(g_part));
  hipGetSymbolAddress((void**)&att2p, HIP_SYMBOL(g_att2p));
  hipGetSymbolAddress((void**)&e, HIP_SYMBOL(g_e));
  hipGetSymbolAddress((void**)&c1, HIP_SYMBOL(g_c1));
  hipGetSymbolAddress((void**)&c2, HIP_SYMBOL(g_c2));
  hipGetSymbolAddress((void**)&ib, HIP_SYMBOL(g_ibuf));
  int* sind = ib;
  int* declen = ib + 64;
  int* caps_s = ib + 128;

  float* out_preds  = out;
  float* out_preds1 = out + (size_t)B_ * TDEC_ * V_;
  float* out_caps   = out + 2ull * B_ * TDEC_ * V_;
  float* out_declen = out_caps + B_ * MAXLEN_;
  float* out_sind   = out_declen + B_;

  // ---- preprocessing ----
  k_sort<<<1, 64, 0, stream>>>(cl, caps, sind, declen, caps_s, out_caps, out_declen, out_sind);
  hipMemsetAsync(c1, 0, 64 * 1024 * sizeof(float), stream);
  hipMemsetAsync(c2, 0, 64 * 1024 * sizeof(float), stream);
  hipMemsetAsync(xs1, 0, (size_t)64 * 2048 * sizeof(short), stream);  // t=0
  hipMemsetAsync(xc2, 0, (size_t)64 * 4096 * sizeof(short), stream);  // t=0
  k_encprep<<<12544, 256, 0, stream>>>(enc, sind, encb, encbt);
  k_encmeanb<<<64, 256, 0, stream>>>(encb, em);
  k_prefill<<<dim3(19, 64), 256, 0, stream>>>(emb, caps_s, em, xmid);
  // weight converts
  k_f2bts<<<2048, 256, 0, stream>>>(Wih1, 4096, 0, 1024, Wp1t, 2048, 0);
  k_f2bts<<<2048, 256, 0, stream>>>(Whh1, 1024, 0, 1024, Wp1t, 2048, 1024);
  k_f2bts<<<6144, 256, 0, stream>>>(Wih1, 4096, 1024, 3072, Wmid1t, 3072, 0);
  k_f2bts<<<6144, 256, 0, stream>>>(Wih2, 3072, 0, 3072, Wc2t, 4096, 0);
  k_f2bts<<<2048, 256, 0, stream>>>(Whh2, 1024, 0, 1024, Wc2t, 4096, 3072);
  k_f2bts<<<1024, 256, 0, stream>>>(We, 2048, 0, 2048, Webt, 2048, 0);
  k_f2bts<<<512, 256, 0, stream>>>(Wd, 1024, 0, 1024, Wdt, 1024, 0);
  k_f2bts<<<5000, 256, 0, stream>>>(Wfc1, 1024, 0, 1024, Wfc1t, 1024, 0);
  k_f2bts<<<5000, 256, 0, stream>>>(Wfc, 1024, 0, 1024, Wfct, 1024, 0);
  k_att1_t<<<dim3(98, 2), 1024, 0, stream>>>(encbt, Webt, be, att1);
  k_mid_bt<<<dim3(32, 19), 256, 0, stream>>>(xmid, Wmid1t, pre1);

  // ---- decode loop ----
  for (int t = 0; t < TDEC_; ++t) {
    short* s1t = xs1 + (size_t)t * 64 * 2048;
    short* s1n = xs1 + (size_t)(t + 1) * 64 * 2048;
    short* x2t = xc2 + (size_t)t * 64 * 4096;
    short* x2n = xc2 + (size_t)(t + 1) * 64 * 4096;
    // LSTM1 step: [h2|h1] @ Wp1^T  (K=2048, KS=8 -> 256)
    k_skinny_t<<<dim3(32, 8), 256, 0, stream>>>(s1t, 2048, Wp1t, 2048, 4096, 256, part);
    k_gates<<<256, 256, 0, stream>>>(part, 8, pre1 + (size_t)t * 64 * 4096,
                                     bih1, bhh1, c1, s1t + 1024, 2048,
                                     s1n + 1024, 2048, x2t + 2048, 4096, declen, t);
    // att2 = h1 @ Wd^T  (K=1024, KS=4 -> 256)
    k_skinny_t<<<dim3(8, 4), 256, 0, stream>>>(x2t + 2048, 4096, Wdt, 1024, 1024, 256, att2p);
    k_e<<<3136, 256, 0, stream>>>(att1, att2p, bd, Wf, bf, e);
    k_sawe<<<dim3(64, 8), 256, 0, stream>>>(e, encb, x2t);
    // LSTM2: [awe|h1|h2] @ Wc2^T  (K=4096, KS=8 -> 512)
    k_skinny_t<<<dim3(32, 8), 256, 0, stream>>>(x2t, 4096, Wc2t, 4096, 4096, 512, part);
    k_gates<<<256, 256, 0, stream>>>(part, 8, nullptr, bih2, bhh2, c2, s1t, 2048,
                                     s1n, 2048, x2n + 3072, 4096, declen, t);
  }
  // ---- batched output heads over all t ----
  k_head4<<<dim3(40, 19), 256, 0, stream>>>(xc2 + 2048, Wfc1t, bfc1, out_preds1, declen);
  k_head4<<<dim3(40, 19), 256, 0, stream>>>(xc2 + 64 * 4096 + 3072, Wfct, bfc, out_preds, declen);
}

// Round 8
// 1865.416 us; speedup vs baseline: 2.1833x; 1.0423x over previous
//
#include <hip/hip_runtime.h>
#include <cmath>

#define B_ 64
#define P_ 196
#define ENC_ 2048
#define DEC_ 1024
#define V_ 10000
#define MAXLEN_ 20
#define TDEC_ 19

typedef __attribute__((ext_vector_type(8))) short bf16x8;
typedef __attribute__((ext_vector_type(4))) float f32x4;

// Tiled weight layout: tile = 16 rows x 32 k = 512 bf16 = 1KB, k-tiles fastest.
// element (r,k): offset = ((r>>4)*(K>>5) + (k>>5))*512 + ((r&15) | (((k>>3)&3)<<4))*8 + (k&7)

// ---------------- static device buffers ----------------
__device__ __align__(16) short g_encb[(size_t)12544 * 2048];    // sorted enc, bf16 row-major
__device__ __align__(16) short g_encbt[(size_t)12544 * 2048];   // sorted enc, bf16 TILED
__device__ __align__(16) short g_att1[(size_t)12544 * 1024];    // att1, bf16 (incl. be)
__device__ __align__(16) short g_Wp1t[(size_t)4096 * 2048];     // [Wih1[:, :1024] | Whh1] tiled
__device__ __align__(16) short g_Wemt[(size_t)4096 * 2048];     // Wih1[:, 1024:3072] tiled
__device__ __align__(16) short g_Wembt[(size_t)4096 * 1024];    // Wih1[:, 3072:4096] tiled
__device__ __align__(16) short g_Wc2t[(size_t)4096 * 4096];     // [Wih2(3072)|Whh2(1024)] tiled
__device__ __align__(16) short g_Webt[(size_t)1024 * 2048];     // We tiled
__device__ __align__(16) short g_Wdt[(size_t)1024 * 1024];      // Wd tiled
__device__ __align__(16) short g_Wfc1t[(size_t)10000 * 1024];   // Wfc1 tiled
__device__ __align__(16) short g_Wfct[(size_t)10000 * 1024];    // Wfc tiled
__device__ __align__(16) short g_xs1[(size_t)20 * 64 * 2048];   // per-t [h2|h1] (LSTM1 step A)
__device__ __align__(16) short g_xemb[(size_t)19 * 64 * 1024];  // per-t emb_t
__device__ __align__(16) short g_xc2[(size_t)20 * 64 * 4096];   // per-t [awe|h1|h2]
__device__ __align__(16) short g_em[64 * 2048];                 // enc mean, bf16
__device__ __align__(16) float g_preemb[(size_t)19 * 64 * 4096]; // per-t emb gate part
__device__ __align__(16) float g_preem[64 * 4096];               // em gate part
__device__ __align__(16) float g_part[(size_t)8 * 64 * 4096];
__device__ __align__(16) float g_att2p[(size_t)4 * 64 * 1024];
__device__ __align__(16) float g_e[64 * P_];
__device__ __align__(16) float g_c1[64 * 1024];
__device__ __align__(16) float g_c2[64 * 1024];
__device__ int g_ibuf[64 + 64 + 64 * MAXLEN_];

__device__ __forceinline__ short f2b(float f) {
  unsigned u = __float_as_uint(f);
  u += 0x7FFFu + ((u >> 16) & 1u);
  return (short)(u >> 16);
}
__device__ __forceinline__ float b2f(short s) {
  return __uint_as_float(((unsigned)(unsigned short)s) << 16);
}

// ---------------- sort + int-ish outputs ----------------
__global__ void k_sort(const int* __restrict__ cl_in, const int* __restrict__ caps_in,
                       int* __restrict__ sind, int* __restrict__ declen, int* __restrict__ caps_s,
                       float* __restrict__ out_caps, float* __restrict__ out_declen,
                       float* __restrict__ out_sind) {
  int i = threadIdx.x;  // 64 threads
  __shared__ int cl[B_];
  cl[i] = cl_in[i];
  __syncthreads();
  int my = cl[i], pos = 0;
  for (int j = 0; j < B_; ++j) {
    int cj = cl[j];
    if (cj > my || (cj == my && j < i)) pos++;
  }
  sind[pos] = i;
  __syncthreads();
  int sb = sind[i];
  int dl = cl[sb] - 1;
  declen[i] = dl;
  out_declen[i] = (float)dl;
  out_sind[i] = (float)sb;
  for (int t = 0; t < MAXLEN_; ++t) {
    int v = caps_in[sb * MAXLEN_ + t];
    caps_s[i * MAXLEN_ + t] = v;
    out_caps[i * MAXLEN_ + t] = (float)v;
  }
}

// gather-sort + fp32->bf16 encoder: row-major AND tiled copies
__global__ __launch_bounds__(256) void k_encprep(const float* __restrict__ enc,
                                                 const int* __restrict__ sind,
                                                 short* __restrict__ encb,
                                                 short* __restrict__ encbt) {
  int mg = blockIdx.x;  // 12544
  int b = mg / P_, p = mg - b * P_;
  int tid = threadIdx.x;
  const float* src = enc + ((size_t)sind[b] * P_ + p) * ENC_ + tid * 8;
  float4 a = *(const float4*)src;
  float4 c = *(const float4*)(src + 4);
  bf16x8 v;
  v[0] = f2b(a.x); v[1] = f2b(a.y); v[2] = f2b(a.z); v[3] = f2b(a.w);
  v[4] = f2b(c.x); v[5] = f2b(c.y); v[6] = f2b(c.z); v[7] = f2b(c.w);
  *(bf16x8*)(encb + (size_t)mg * ENC_ + tid * 8) = v;
  size_t off = (((size_t)(mg >> 4) * 64 + (tid >> 2)) << 9) +
               (((mg & 15) | ((tid & 3) << 4)) << 3);
  *(bf16x8*)(encbt + off) = v;
}

// enc mean -> g_em (bf16)
__global__ __launch_bounds__(256) void k_encmeanb(const short* __restrict__ encb,
                                                  short* __restrict__ em) {
  int b = blockIdx.x;
  int col0 = threadIdx.x * 8;
  const short* src = encb + (size_t)b * P_ * ENC_ + col0;
  float acc[8] = {};
  for (int p = 0; p < P_; ++p) {
    bf16x8 v = *(const bf16x8*)(src + (size_t)p * ENC_);
#pragma unroll
    for (int j = 0; j < 8; ++j) acc[j] += b2f(v[j]);
  }
#pragma unroll
  for (int j = 0; j < 8; ++j) em[b * 2048 + col0 + j] = f2b(acc[j] * (1.0f / 196.0f));
}

// prefill xemb[t][b] = emb table row of caps[b][t]
__global__ __launch_bounds__(256) void k_prefill(const float* __restrict__ emb,
                                                 const int* __restrict__ caps_s,
                                                 short* __restrict__ xemb) {
  int t = blockIdx.x, b = blockIdx.y, tid = threadIdx.x;  // (19, 64)
  short* xr = xemb + ((size_t)t * 64 + b) * 1024;
  int cap = caps_s[b * MAXLEN_ + t];
  int j = tid * 4;
  float4 v = *(const float4*)(emb + (size_t)cap * 1024 + j);
  short4 o;
  o.x = f2b(v.x); o.y = f2b(v.y); o.z = f2b(v.z); o.w = f2b(v.w);
  *(short4*)(xr + j) = o;
}

// fp32 row-major src[r][Kstride], col-slice [c0, c0+ncols) -> bf16 TILED dst (Ktot, koff)
__global__ void k_f2bts(const float* __restrict__ src, int Kstride, int c0, int ncols,
                        short* __restrict__ dst, int Ktot, int koff) {
  int idx = blockIdx.x * 256 + threadIdx.x;
  int kc = ncols >> 3;
  int r = idx / kc, k8 = (idx - r * kc) << 3;
  const float* s = src + (size_t)r * Kstride + c0 + k8;
  float4 a = *(const float4*)s;
  float4 c = *(const float4*)(s + 4);
  bf16x8 v;
  v[0] = f2b(a.x); v[1] = f2b(a.y); v[2] = f2b(a.z); v[3] = f2b(a.w);
  v[4] = f2b(c.x); v[5] = f2b(c.y); v[6] = f2b(c.z); v[7] = f2b(c.w);
  int kg = koff + k8;
  size_t off = (((size_t)(r >> 4) * (Ktot >> 5) + (kg >> 5)) << 9) +
               (((r & 15) | (((kg >> 3) & 3) << 4)) << 3);
  *(bf16x8*)(dst + off) = v;
}

// ---------------- att1 = enc @ We^T + be -> bf16 (12544x1024), both TILED ----------------
__global__ __launch_bounds__(1024) void k_att1_t(const short* __restrict__ At,
                                                 const short* __restrict__ Wt,
                                                 const float* __restrict__ be,
                                                 short* __restrict__ Cb) {
  int wave = threadIdx.x >> 6, lane = threadIdx.x & 63;
  int mt0 = blockIdx.x * 8 + (wave >> 3) * 4;
  int nt0 = blockIdx.y * 32 + (wave & 7) * 4;
  f32x4 acc[4][4] = {};
  const short* Ab = At + ((size_t)mt0 * 64 << 9) + lane * 8;  // 64 k-tiles
  const short* Wb = Wt + ((size_t)nt0 * 64 << 9) + lane * 8;
  for (int kt = 0; kt < 64; ++kt) {
    bf16x8 a[4], b[4];
#pragma unroll
    for (int i = 0; i < 4; ++i) a[i] = *(const bf16x8*)(Ab + (((size_t)i * 64 + kt) << 9));
#pragma unroll
    for (int j = 0; j < 4; ++j) b[j] = *(const bf16x8*)(Wb + (((size_t)j * 64 + kt) << 9));
#pragma unroll
    for (int i = 0; i < 4; ++i)
#pragma unroll
      for (int j = 0; j < 4; ++j)
        acc[i][j] = __builtin_amdgcn_mfma_f32_16x16x32_bf16(a[i], b[j], acc[i][j], 0, 0, 0);
  }
  int rr = (lane >> 4) * 4, cc = lane & 15;
  int m0 = mt0 * 16, n0 = nt0 * 16;
#pragma unroll
  for (int i = 0; i < 4; ++i)
#pragma unroll
    for (int j = 0; j < 4; ++j) {
      int n = n0 + j * 16 + cc;
      float bn = be[n];
#pragma unroll
      for (int r = 0; r < 4; ++r) {
        int m = m0 + i * 16 + rr + r;
        Cb[(size_t)m * 1024 + n] = f2b(acc[i][j][r] + bn);
      }
    }
}

// ---------------- skinny MFMA GEMM, tiled W: part[s][64][N] ----------------
__global__ __launch_bounds__(256) void k_skinny_t(const short* __restrict__ A, int lda,
                                                  const short* __restrict__ Wt, int ldw,
                                                  int N, int kchunk, float* __restrict__ part) {
  int wave = threadIdx.x >> 6, lane = threadIdx.x & 63;
  int n0 = blockIdx.x * 128 + wave * 32;
  int kb = blockIdx.y * kchunk;
  int lr = lane & 15, lk = (lane >> 4) * 8;
  int ntk = ldw >> 5;
  int nt0 = n0 >> 4;
  f32x4 acc[4][2] = {};
  const short* Ab = A + (size_t)lr * lda + kb + lk;
  const short* Wb0 = Wt + (((size_t)nt0 * ntk + (kb >> 5)) << 9) + lane * 8;
  const short* Wb1 = Wt + (((size_t)(nt0 + 1) * ntk + (kb >> 5)) << 9) + lane * 8;
  int nkt = kchunk >> 5;
  for (int kt = 0; kt < nkt; ++kt) {
    bf16x8 a[4], b0, b1;
#pragma unroll
    for (int i = 0; i < 4; ++i) a[i] = *(const bf16x8*)(Ab + (size_t)i * 16 * lda + kt * 32);
    b0 = *(const bf16x8*)(Wb0 + ((size_t)kt << 9));
    b1 = *(const bf16x8*)(Wb1 + ((size_t)kt << 9));
#pragma unroll
    for (int i = 0; i < 4; ++i) {
      acc[i][0] = __builtin_amdgcn_mfma_f32_16x16x32_bf16(a[i], b0, acc[i][0], 0, 0, 0);
      acc[i][1] = __builtin_amdgcn_mfma_f32_16x16x32_bf16(a[i], b1, acc[i][1], 0, 0, 0);
    }
  }
  float* po = part + (size_t)blockIdx.y * 64 * N;
  int rr = (lane >> 4) * 4, cc = lane & 15;
#pragma unroll
  for (int i = 0; i < 4; ++i)
#pragma unroll
    for (int j = 0; j < 2; ++j) {
      int n = n0 + j * 16 + cc;
#pragma unroll
      for (int r = 0; r < 4; ++r) {
        int m = i * 16 + rr + r;
        po[(size_t)m * N + n] = acc[i][j][r];
      }
    }
}

// sum nsplit partial planes into dst (64*4096 elems)
__global__ void k_sumn(const float* __restrict__ part, int nsplit, float* __restrict__ dst) {
  int idx = blockIdx.x * 256 + threadIdx.x;
  float s = 0.0f;
  for (int q = 0; q < nsplit; ++q) s += part[(size_t)q * 64 * 4096 + idx];
  dst[idx] = s;
}

// ---------------- batched emb GEMM: preemb[t][64][4096] = xemb[t] @ Wemb^T (K=1024) ----------------
// grid (19, 16): x = t so consecutive blocks share the W n-slice (L2 reuse); 4 nt per wave.
__global__ __launch_bounds__(256) void k_mid_emb4(const short* __restrict__ xemb,
                                                  const short* __restrict__ Wt,
                                                  float* __restrict__ preemb) {
  int t = blockIdx.x;
  const short* A = xemb + (size_t)t * 64 * 1024;
  int wave = threadIdx.x >> 6, lane = threadIdx.x & 63;
  int nt0 = blockIdx.y * 16 + wave * 4;  // 256 n-tiles total
  int lr = lane & 15, lk = (lane >> 4) * 8;
  f32x4 acc[4][4] = {};
  const short* Ab = A + (size_t)lr * 1024 + lk;
  const short* Wb[4];
#pragma unroll
  for (int j = 0; j < 4; ++j) Wb[j] = Wt + ((size_t)(nt0 + j) * 32 << 9) + lane * 8;
  for (int kt = 0; kt < 32; ++kt) {
    bf16x8 a[4], b[4];
#pragma unroll
    for (int j = 0; j < 4; ++j) b[j] = *(const bf16x8*)(Wb[j] + ((size_t)kt << 9));
#pragma unroll
    for (int i = 0; i < 4; ++i) a[i] = *(const bf16x8*)(Ab + (size_t)i * 16 * 1024 + kt * 32);
#pragma unroll
    for (int i = 0; i < 4; ++i)
#pragma unroll
      for (int j = 0; j < 4; ++j)
        acc[i][j] = __builtin_amdgcn_mfma_f32_16x16x32_bf16(a[i], b[j], acc[i][j], 0, 0, 0);
  }
  float* po = preemb + (size_t)t * 64 * 4096;
  int rr = (lane >> 4) * 4, cc = lane & 15;
#pragma unroll
  for (int i = 0; i < 4; ++i)
#pragma unroll
    for (int j = 0; j < 4; ++j) {
      int n = (nt0 + j) * 16 + cc;
#pragma unroll
      for (int r = 0; r < 4; ++r) {
        int m = i * 16 + rr + r;
        po[(size_t)m * 4096 + n] = acc[i][j][r];
      }
    }
}

// ---------------- LSTM gates: biases + nsplit partials (+ pre, pre2), update c, forward h ----------------
__global__ void k_gates(const float* __restrict__ part, int nsplit,
                        const float* __restrict__ pre, const float* __restrict__ pre2,
                        const float* __restrict__ bih, const float* __restrict__ bhh,
                        float* __restrict__ c,
                        const short* __restrict__ hold, int ldo,
                        short* __restrict__ dst1, int ld1,
                        short* __restrict__ dst2, int ld2,
                        const int* __restrict__ declen, int t) {
  int idx = blockIdx.x * 256 + threadIdx.x;  // 65536
  int b = idx >> 10, j = idx & 1023;
  const float* pb = part + (size_t)b * 4096;
  float gi = bih[j] + bhh[j];
  float gf = bih[1024 + j] + bhh[1024 + j];
  float gg = bih[2048 + j] + bhh[2048 + j];
  float go = bih[3072 + j] + bhh[3072 + j];
  if (pre) {
    const float* pp = pre + (size_t)b * 4096;
    gi += pp[j]; gf += pp[j + 1024]; gg += pp[j + 2048]; go += pp[j + 3072];
  }
  if (pre2) {
    const float* pp = pre2 + (size_t)b * 4096;
    gi += pp[j]; gf += pp[j + 1024]; gg += pp[j + 2048]; go += pp[j + 3072];
  }
  for (int s = 0; s < nsplit; ++s) {
    const float* p = pb + (size_t)s * 64 * 4096;
    gi += p[j]; gf += p[j + 1024]; gg += p[j + 2048]; go += p[j + 3072];
  }
  float si = 1.0f / (1.0f + expf(-gi));
  float sf = 1.0f / (1.0f + expf(-gf));
  float so = 1.0f / (1.0f + expf(-go));
  float cn = sf * c[idx] + si * tanhf(gg);
  float hn = so * tanhf(cn);
  short hb;
  if (t < declen[b]) {
    c[idx] = cn;
    hb = f2b(hn);
  } else {
    hb = hold[b * ldo + j];
  }
  dst1[b * ld1 + j] = hb;
  dst2[b * ld2 + j] = hb;
}

// ---------------- e[b,p] = Wf . relu(att1[b,p,:] + att2) + bf ----------------
__global__ __launch_bounds__(256) void k_e(const short* __restrict__ att1,
                                           const float* __restrict__ att2p,
                                           const float* __restrict__ bd,
                                           const float* __restrict__ Wf,
                                           const float* __restrict__ bf,
                                           float* __restrict__ e) {
  __shared__ float a2[1024];
  int b = blockIdx.x / 49, pq = blockIdx.x % 49;
  for (int i = threadIdx.x; i < 1024; i += 256) {
    float s = bd[i];
#pragma unroll
    for (int q = 0; q < 4; ++q) s += att2p[q * 65536 + b * 1024 + i];
    a2[i] = s;
  }
  __syncthreads();
  int wave = threadIdx.x >> 6, lane = threadIdx.x & 63;
  int p = pq * 4 + wave;
  const short* a1 = att1 + ((size_t)(b * P_ + p)) * 1024;
  float s = 0.0f;
#pragma unroll
  for (int h = 0; h < 2; ++h) {
    int k0 = lane * 8 + h * 512;
    bf16x8 v = *(const bf16x8*)(a1 + k0);
#pragma unroll
    for (int j = 0; j < 8; ++j) s += Wf[k0 + j] * fmaxf(b2f(v[j]) + a2[k0 + j], 0.0f);
  }
#pragma unroll
  for (int off = 32; off; off >>= 1) s += __shfl_down(s, off);
  if (lane == 0) e[b * P_ + p] = s + bf[0];
}

// ---------------- softmax (in-block) + awe ----------------
__global__ __launch_bounds__(256) void k_sawe(const float* __restrict__ e,
                                              const short* __restrict__ encb,
                                              short* __restrict__ xc2t) {
  int b = blockIdx.x, ch = blockIdx.y;  // ch < 8
  __shared__ float al[P_];
  __shared__ float red[8][256];
  int tid = threadIdx.x;
  if (tid < 64) {
    float vals[4];
    float mx = -1e30f;
#pragma unroll
    for (int q = 0; q < 4; ++q) {
      int p = tid + q * 64;
      vals[q] = (p < P_) ? e[b * P_ + p] : -1e30f;
      mx = fmaxf(mx, vals[q]);
    }
#pragma unroll
    for (int off = 32; off; off >>= 1) mx = fmaxf(mx, __shfl_xor(mx, off));
    float sum = 0.0f;
#pragma unroll
    for (int q = 0; q < 4; ++q) {
      int p = tid + q * 64;
      vals[q] = (p < P_) ? expf(vals[q] - mx) : 0.0f;
      sum += vals[q];
    }
#pragma unroll
    for (int off = 32; off; off >>= 1) sum += __shfl_xor(sum, off);
    float inv = 1.0f / sum;
#pragma unroll
    for (int q = 0; q < 4; ++q) {
      int p = tid + q * 64;
      if (p < P_) al[p] = vals[q] * inv;
    }
  }
  __syncthreads();
  int pg = tid >> 5, cg = tid & 31;
  int col = ch * 256 + cg * 8;
  const short* src = encb + (size_t)b * P_ * ENC_ + col;
  float acc[8] = {};
  for (int p = pg; p < P_; p += 8) {
    bf16x8 v = *(const bf16x8*)(src + (size_t)p * ENC_);
    float ap = al[p];
#pragma unroll
    for (int j = 0; j < 8; ++j) acc[j] += ap * b2f(v[j]);
  }
#pragma unroll
  for (int j = 0; j < 8; ++j) red[pg][cg * 8 + j] = acc[j];
  __syncthreads();
  float s = 0.0f;
#pragma unroll
  for (int g = 0; g < 8; ++g) s += red[g][tid];
  xc2t[b * 4096 + ch * 256 + tid] = f2b(s);
}

// ---------------- batched head GEMM: 4 nt per wave, grid (19, 40) for W L2 reuse ----------------
__global__ __launch_bounds__(256) void k_head4(const short* __restrict__ Aall,
                                               const short* __restrict__ Wt,
                                               const float* __restrict__ bias,
                                               float* __restrict__ outp,
                                               const int* __restrict__ declen) {
  int t = blockIdx.x;
  const short* A = Aall + (size_t)t * (64 * 4096);
  int wave = threadIdx.x >> 6, lane = threadIdx.x & 63;
  int nt0 = blockIdx.y * 16 + wave * 4;  // 4 n-tiles per wave; 625 total
  int lr = lane & 15, lk = (lane >> 4) * 8;
  f32x4 acc[4][4] = {};
  const short* Ab = A + (size_t)lr * 4096 + lk;
  const short* Wb[4];
  bool ok[4];
#pragma unroll
  for (int j = 0; j < 4; ++j) {
    ok[j] = (nt0 + j) < (V_ >> 4);
    Wb[j] = Wt + ((size_t)(ok[j] ? nt0 + j : 0) * 32 << 9) + lane * 8;
  }
  for (int kt = 0; kt < 32; ++kt) {
    bf16x8 a[4], b[4];
#pragma unroll
    for (int j = 0; j < 4; ++j) b[j] = *(const bf16x8*)(Wb[j] + ((size_t)kt << 9));
#pragma unroll
    for (int i = 0; i < 4; ++i) a[i] = *(const bf16x8*)(Ab + (size_t)i * 16 * 4096 + kt * 32);
#pragma unroll
    for (int i = 0; i < 4; ++i)
#pragma unroll
      for (int j = 0; j < 4; ++j)
        acc[i][j] = __builtin_amdgcn_mfma_f32_16x16x32_bf16(a[i], b[j], acc[i][j], 0, 0, 0);
  }
  int rr = (lane >> 4) * 4, cc = lane & 15;
#pragma unroll
  for (int j = 0; j < 4; ++j) {
    if (!ok[j]) continue;
    int n = (nt0 + j) * 16 + cc;
    float bn = bias[n];
#pragma unroll
    for (int i = 0; i < 4; ++i) {
#pragma unroll
      for (int r = 0; r < 4; ++r) {
        int b = i * 16 + rr + r;
        float val = acc[i][j][r] + bn;
        outp[((size_t)b * TDEC_ + t) * V_ + n] = (t < declen[b]) ? val : 0.0f;
      }
    }
  }
}

// ---------------- host ----------------
extern "C" void kernel_launch(void* const* d_in, const int* in_sizes, int n_in,
                              void* d_out, int out_size, void* d_ws, size_t ws_size,
                              hipStream_t stream) {
  (void)in_sizes; (void)n_in; (void)d_ws; (void)ws_size; (void)out_size;
  const float* enc  = (const float*)d_in[0];
  const int*   caps = (const int*)d_in[1];
  const int*   cl   = (const int*)d_in[2];
  const float* emb  = (const float*)d_in[3];
  const float* We   = (const float*)d_in[4];
  const float* be   = (const float*)d_in[5];
  const float* Wd   = (const float*)d_in[6];
  const float* bd   = (const float*)d_in[7];
  const float* Wf   = (const float*)d_in[8];
  const float* bf   = (const float*)d_in[9];
  const float* Wih1 = (const float*)d_in[10];
  const float* Whh1 = (const float*)d_in[11];
  const float* bih1 = (const float*)d_in[12];
  const float* bhh1 = (const float*)d_in[13];
  const float* Wih2 = (const float*)d_in[14];
  const float* Whh2 = (const float*)d_in[15];
  const float* bih2 = (const float*)d_in[16];
  const float* bhh2 = (const float*)d_in[17];
  const float* Wfc1 = (const float*)d_in[18];
  const float* bfc1 = (const float*)d_in[19];
  const float* Wfc  = (const float*)d_in[20];
  const float* bfc  = (const float*)d_in[21];
  float* out = (float*)d_out;

  short *encb, *encbt, *att1, *Wp1t, *Wemt, *Wembt, *Wc2t, *Webt, *Wdt, *Wfc1t, *Wfct;
  short *xs1, *xemb, *xc2, *em;
  float *preemb, *preem, *part, *att2p, *e, *c1, *c2;
  int* ib;
  hipGetSymbolAddress((void**)&encb, HIP_SYMBOL(g_encb));
  hipGetSymbolAddress((void**)&encbt, HIP_SYMBOL(g_encbt));
  hipGetSymbolAddress((void**)&att1, HIP_SYMBOL(g_att1));
  hipGetSymbolAddress((void**)&Wp1t, HIP_SYMBOL(g_Wp1t));
  hipGetSymbolAddress((void**)&Wemt, HIP_SYMBOL(g_Wemt));
  hipGetSymbolAddress((void**)&Wembt, HIP_SYMBOL(g_Wembt));
  hipGetSymbolAddress((void**)&Wc2t, HIP_SYMBOL(g_Wc2t));
  hipGetSymbolAddress((void**)&Webt, HIP_SYMBOL(g_Webt));
  hipGetSymbolAddress((void**)&Wdt, HIP_SYMBOL(g_Wdt));
  hipGetSymbolAddress((void**)&Wfc1t, HIP_SYMBOL(g_Wfc1t));
  hipGetSymbolAddress((void**)&Wfct, HIP_SYMBOL(g_Wfct));
  hipGetSymbolAddress((void**)&xs1, HIP_SYMBOL(g_xs1));
  hipGetSymbolAddress((void**)&xemb, HIP_SYMBOL(g_xemb));
  hipGetSymbolAddress((void**)&xc2, HIP_SYMBOL(g_xc2));
  hipGetSymbolAddress((void**)&em, HIP_SYMBOL(g_em));
  hipGetSymbolAddress((void**)&preemb, HIP_SYMBOL(g_preemb));
  hipGetSymbolAddress((void**)&preem, HIP_SYMBOL(g_preem));
  hipGetSymbolAddress((void**)&part, HIP_SYMBOL(g_part));
  hipGetSymbolAddress((void**)&att2p, HIP_SYMBOL(g_att2p));
  hipGetSymbolAddress((void**)&e, HIP_SYMBOL(g_e));
  hipGetSymbolAddress((void**)&c1, HIP_SYMBOL(g_c1));
  hipGetSymbolAddress((void**)&c2, HIP_SYMBOL(g_c2));
  hipGetSymbolAddress((void**)&ib, HIP_SYMBOL(g_ibuf));
  int* sind = ib;
  int* declen = ib + 64;
  int* caps_s = ib + 128;

  float* out_preds  = out;
  float* out_preds1 = out + (size_t)B_ * TDEC_ * V_;
  float* out_caps   = out + 2ull * B_ * TDEC_ * V_;
  float* out_declen = out_caps + B_ * MAXLEN_;
  float* out_sind   = out_declen + B_;

  // ---- preprocessing ----
  k_sort<<<1, 64, 0, stream>>>(cl, caps, sind, declen, caps_s, out_caps, out_declen, out_sind);
  hipMemsetAsync(c1, 0, 64 * 1024 * sizeof(float), stream);
  hipMemsetAsync(c2, 0, 64 * 1024 * sizeof(float), stream);
  hipMemsetAsync(xs1, 0, (size_t)64 * 2048 * sizeof(short), stream);  // t=0
  hipMemsetAsync(xc2, 0, (size_t)64 * 4096 * sizeof(short), stream);  // t=0
  k_encprep<<<12544, 256, 0, stream>>>(enc, sind, encb, encbt);
  k_encmeanb<<<64, 256, 0, stream>>>(encb, em);
  k_prefill<<<dim3(19, 64), 256, 0, stream>>>(emb, caps_s, xemb);
  // weight converts
  k_f2bts<<<2048, 256, 0, stream>>>(Wih1, 4096, 0, 1024, Wp1t, 2048, 0);
  k_f2bts<<<2048, 256, 0, stream>>>(Whh1, 1024, 0, 1024, Wp1t, 2048, 1024);
  k_f2bts<<<4096, 256, 0, stream>>>(Wih1, 4096, 1024, 2048, Wemt, 2048, 0);
  k_f2bts<<<2048, 256, 0, stream>>>(Wih1, 4096, 3072, 1024, Wembt, 1024, 0);
  k_f2bts<<<6144, 256, 0, stream>>>(Wih2, 3072, 0, 3072, Wc2t, 4096, 0);
  k_f2bts<<<2048, 256, 0, stream>>>(Whh2, 1024, 0, 1024, Wc2t, 4096, 3072);
  k_f2bts<<<1024, 256, 0, stream>>>(We, 2048, 0, 2048, Webt, 2048, 0);
  k_f2bts<<<512, 256, 0, stream>>>(Wd, 1024, 0, 1024, Wdt, 1024, 0);
  k_f2bts<<<5000, 256, 0, stream>>>(Wfc1, 1024, 0, 1024, Wfc1t, 1024, 0);
  k_f2bts<<<5000, 256, 0, stream>>>(Wfc, 1024, 0, 1024, Wfct, 1024, 0);
  k_att1_t<<<dim3(98, 2), 1024, 0, stream>>>(encbt, Webt, be, att1);
  // em contribution to LSTM1 gates (once): em @ Wem^T, KS=4, then sum
  k_skinny_t<<<dim3(32, 4), 256, 0, stream>>>(em, 2048, Wemt, 2048, 4096, 512, part);
  k_sumn<<<1024, 256, 0, stream>>>(part, 4, preem);
  // emb contribution per t (batched)
  k_mid_emb4<<<dim3(19, 16), 256, 0, stream>>>(xemb, Wembt, preemb);

  // ---- decode loop ----
  for (int t = 0; t < TDEC_; ++t) {
    short* s1t = xs1 + (size_t)t * 64 * 2048;
    short* s1n = xs1 + (size_t)(t + 1) * 64 * 2048;
    short* x2t = xc2 + (size_t)t * 64 * 4096;
    short* x2n = xc2 + (size_t)(t + 1) * 64 * 4096;
    // LSTM1 step: [h2|h1] @ Wp1^T  (K=2048, KS=8 -> 256)
    k_skinny_t<<<dim3(32, 8), 256, 0, stream>>>(s1t, 2048, Wp1t, 2048, 4096, 256, part);
    k_gates<<<256, 256, 0, stream>>>(part, 8, preemb + (size_t)t * 64 * 4096, preem,
                                     bih1, bhh1, c1, s1t + 1024, 2048,
                                     s1n + 1024, 2048, x2t + 2048, 4096, declen, t);
    // att2 = h1 @ Wd^T  (K=1024, KS=4 -> 256)
    k_skinny_t<<<dim3(8, 4), 256, 0, stream>>>(x2t + 2048, 4096, Wdt, 1024, 1024, 256, att2p);
    k_e<<<3136, 256, 0, stream>>>(att1, att2p, bd, Wf, bf, e);
    k_sawe<<<dim3(64, 8), 256, 0, stream>>>(e, encb, x2t);
    // LSTM2: [awe|h1|h2] @ Wc2^T  (K=4096, KS=8 -> 512)
    k_skinny_t<<<dim3(32, 8), 256, 0, stream>>>(x2t, 4096, Wc2t, 4096, 4096, 512, part);
    k_gates<<<256, 256, 0, stream>>>(part, 8, nullptr, nullptr, bih2, bhh2, c2, s1t, 2048,
                                     s1n, 2048, x2n + 3072, 4096, declen, t);
  }
  // ---- batched output heads over all t ----
  k_head4<<<dim3(19, 40), 256, 0, stream>>>(xc2 + 2048, Wfc1t, bfc1, out_preds1, declen);
  k_head4<<<dim3(19, 40), 256, 0, stream>>>(xc2 + 64 * 4096 + 3072, Wfct, bfc, out_preds, declen);
}